// Round 18
// baseline (221.596 us; speedup 1.0000x reference)
//
#include <hip/hip_runtime.h>
#include <math.h>

// Problem constants
#define NQ    128
#define ND    512
#define NDB   100000
#define NDBP  100096            // padded to multiple of 128 (and 32)
#define MM    10
#define KK    10
#define TOPX  3
#define R2    (NQ * MM)         // 1280

// GEMM tiling
#define QB1    128              // stage-1 q rows per block
#define NB1    32               // stage-1 db rows per block (16 loads/thread)
#define NCH1   (NDBP / NB1)     // 3128
#define QB2    256              // stage-2 q rows per block
#define NB     128              // stage-2 db rows per block
#define KT     64               // K elems per stage chunk (one i8 MFMA K-step)
#define NKIT   (ND / KT)        // 8
#define NCHUNK (NDBP / NB)      // 782

// Candidate filtering
#define Z0    3.125f            // stage-1 threshold = Z0 * ||row||
#define Z2    3.3f              // stage-2 threshold (10th-best ~ 4.29||q||)
#define QSC   32.0f             // i8 quantization scale
#define CAP   384               // max candidates per row
#define NROWT (NQ + R2)         // 1408 rows with thresholds

typedef int i32x4 __attribute__((ext_vector_type(4)));

// counted-vmcnt pipeline barrier (gemm2s): wait + barrier fused in one asm.
#define PIPE_BAR(VM) asm volatile("s_waitcnt vmcnt(" #VM ")\n\ts_barrier" ::: "memory")
#define LGKM_BAR()   asm volatile("s_waitcnt lgkmcnt(0)\n\ts_barrier" ::: "memory")

__device__ __forceinline__ void gload_lds16(const void* gsrc, void* ldst) {
    __builtin_amdgcn_global_load_lds(
        (const __attribute__((address_space(1))) unsigned int*)gsrc,
        (__attribute__((address_space(3))) unsigned int*)ldst, 16, 0, 0);
}

__device__ __forceinline__ signed char f2i8(float x) {
    int v = (int)rintf(x * QSC);
    v = v > 127 ? 127 : v;
    v = v < -127 ? -127 : v;
    return (signed char)v;
}

// ---------------------------------------------------------------------------
// Stage-1 query prep: quantize to i8, integer threshold, zero cnt row.
// ---------------------------------------------------------------------------
__global__ __launch_bounds__(256) void prep_q_kernel(
    const float* __restrict__ src, signed char* __restrict__ dst,
    int* __restrict__ thrI, int* __restrict__ cnt)
{
    const int row = blockIdx.x;
    const int t = (int)threadIdx.x;
    __shared__ float red[4];
    const float a = src[(size_t)row * ND + t];
    const float b = src[(size_t)row * ND + t + 256];
    dst[(size_t)row * ND + t] = f2i8(a);
    dst[(size_t)row * ND + t + 256] = f2i8(b);
    float ss = a * a + b * b;
    for (int off = 32; off; off >>= 1) ss += __shfl_xor(ss, off);
    if ((t & 63) == 0) red[t >> 6] = ss;
    __syncthreads();
    if (t == 0) {
        const float tot = red[0] + red[1] + red[2] + red[3];
        thrI[row] = (int)(QSC * QSC * Z0 * sqrtf(tot));
        cnt[row] = 0;
    }
}

// ---------------------------------------------------------------------------
// Stage-1 FUSED cvt+GEMM v5 (pathA). NB1=32 rows/block (3128 blocks).
//   phase 1: ALL 16 float4 loads of the thread's 256B share issued UPFRONT
//            (before any store) -> load-uses never wait behind store
//            retirement in the in-order vmcnt stream (r15/r17 store-gating
//            theory). Then cvt + 4 i8 stores to global dbi8.
//   barrier: __syncthreads drains vmcnt -> stores L2-visible.
//   phase 2: simple 2-barrier dbuf GEMM, D readback via global_load_lds
//            (L2-hot). Per-wave 64x16, acc[4][1]. LDS ~21 KB.
// Chunk validity is block-uniform: NDB = 3125*32, so blocks 0..3124 fully
// valid, 3125..3127 pure padding (write zeros; GEMM yields no candidates).
// ---------------------------------------------------------------------------
__global__ __launch_bounds__(256) void gemm1c_kernel(
    const signed char* __restrict__ Qb,   // [NQ][512] i8
    const float* __restrict__ Df,         // [NDB][512] f32
    signed char* __restrict__ DbOut,      // [NDBP][512] i8 out
    const int* __restrict__ thrI,
    int* __restrict__ candCnt, int* __restrict__ candId)
{
    __shared__ char qlds[2][8192];        // Q K-step tile, dbuf
    __shared__ char dlds[2][2048];        // D K-step tile (32 rows), dbuf
    __shared__ int thrS[QB1];

    const int tid = (int)threadIdx.x;
    const int ln = tid & 63;
    const int wv = tid >> 6;
    const int wr = wv >> 1;               // 0..1 (q half of 128)
    const int wc = wv & 1;                // 0..1 (n half of 32 -> 16 each)
    const int n0 = blockIdx.x * NB1;
    const bool valid = (n0 + NB1 <= NDB); // block-uniform (NDB % 32 == 0)

    if (tid < QB1) thrS[tid] = thrI[tid];

    // ---- phase 1: 16 loads upfront, then cvt + 4 stores ----
    {
        const size_t base = (size_t)n0 * ND;          // float offset
        const size_t toff = base + (size_t)tid * 64;  // 64 floats/thread
        float4 f[16];
        if (valid) {
            const float4* p = (const float4*)(Df + toff);
#pragma unroll
            for (int j = 0; j < 16; ++j) f[j] = p[j];   // ALL loads issued first
#pragma unroll
            for (int k = 0; k < 4; ++k) {               // 4 stores of 16 i8
                union { signed char c[16]; i32x4 v; } u;
#pragma unroll
                for (int j = 0; j < 4; ++j) {
                    const float4 ff = f[k * 4 + j];
                    u.c[j * 4 + 0] = f2i8(ff.x);
                    u.c[j * 4 + 1] = f2i8(ff.y);
                    u.c[j * 4 + 2] = f2i8(ff.z);
                    u.c[j * 4 + 3] = f2i8(ff.w);
                }
                *(i32x4*)(DbOut + toff + (size_t)k * 16) = u.v;
            }
        } else {
            const i32x4 z = {0, 0, 0, 0};
#pragma unroll
            for (int k = 0; k < 4; ++k)
                *(i32x4*)(DbOut + toff + (size_t)k * 16) = z;
        }
    }
    __syncthreads();   // drains vmcnt(0): stores visible in own L2

    i32x4 acc[4][1] = {};

    auto stageQ = [&](int kc, int buf) {
#pragma unroll
        for (int c = 0; c < 2; ++c) {
            const int U = c * 256 + tid;               // 512 units (8 KB)
            const int r = U >> 2;                      // 0..127
            const int u = (U & 3) ^ ((r >> 1) & 3);
            gload_lds16(Qb + (size_t)r * ND + kc + u * 16,
                        qlds[buf] + U * 16);
        }
    };
    auto stageD = [&](int kc, int buf) {
        if (tid < 128) {                               // 128 units (2 KB)
            const int U = tid;
            const int r = U >> 2;                      // 0..31
            const int u = (U & 3) ^ ((r >> 1) & 3);
            gload_lds16(DbOut + (size_t)(n0 + r) * ND + kc + u * 16,
                        dlds[buf] + U * 16);
        }
    };
    auto compute = [&](int buf) {
        const char* Qt = qlds[buf];
        const char* Dt = dlds[buf];
        i32x4 a[4], b;
#pragma unroll
        for (int qt = 0; qt < 4; ++qt) {
            const int r = wr * 64 + qt * 16 + (ln & 15);
            const int u = (ln >> 4) ^ ((r >> 1) & 3);
            a[qt] = *(const i32x4*)(Qt + r * 64 + u * 16);
        }
        {
            const int r = wc * 16 + (ln & 15);
            const int u = (ln >> 4) ^ ((r >> 1) & 3);
            b = *(const i32x4*)(Dt + r * 64 + u * 16);
        }
        __builtin_amdgcn_s_setprio(1);
#pragma unroll
        for (int qt = 0; qt < 4; ++qt)
            acc[qt][0] = __builtin_amdgcn_mfma_i32_16x16x64_i8(
                a[qt], b, acc[qt][0], 0, 0, 0);
        __builtin_amdgcn_s_setprio(0);
    };

    stageQ(0, 0); stageD(0, 0);
    for (int it = 0; it < NKIT; ++it) {
        const int buf = it & 1;
        __syncthreads();                 // stages into buf complete
        if (it + 1 < NKIT) { stageQ((it + 1) * KT, buf ^ 1); stageD((it + 1) * KT, buf ^ 1); }
        compute(buf);
        __syncthreads();                 // done reading buf
    }

    // Threshold filter. C/D layout: col=lane&15, row=(lane>>4)*4+reg.
    const int lg = ln >> 4;
    const int lc = ln & 15;
#pragma unroll
    for (int qt = 0; qt < 4; ++qt) {
#pragma unroll
        for (int c = 0; c < 4; ++c) {
            const int rloc = wr * 64 + qt * 16 + lg * 4 + c;
            const int T = thrS[rloc];
            const int v = acc[qt][0][c];
            if (v > T) {
                const int n = n0 + wc * 16 + lc;
                if (n < NDB) {
                    const int slot = atomicAdd(&candCnt[rloc], 1);
                    if (slot < CAP) candId[(size_t)rloc * CAP + slot] = n;
                }
            }
        }
    }
}

// ---------------------------------------------------------------------------
// Stage-2 GEMM (pathA): XCD-aware chunk grouping (round-8 proven winner).
// Flat grid 3920 (= 8 XCDs x 490 slots). Block 512 = 8 waves (4x2),
// per-wave 64x64, acc[4][4]. LDS 48KB, PIPE_BAR(3) pipeline.
// ---------------------------------------------------------------------------
__global__ __launch_bounds__(512) void gemm2s_kernel(
    const signed char* __restrict__ Qb,   // [R2][512] i8
    const signed char* __restrict__ Db,   // [NDBP][512] i8
    const int* __restrict__ thrI,
    int* __restrict__ candCnt, int* __restrict__ candId)
{
    const int bid = (int)blockIdx.x;
    const int xcd = bid & 7;
    const int slot = bid >> 3;                       // 0..489
    const int nch_x = (xcd < 6) ? 98 : 97;
    if (slot >= nch_x * 5) return;
    const int cstart = (xcd < 6) ? 98 * xcd : 98 * 6 + 97 * (xcd - 6);
    const int chunk = cstart + slot / 5;
    const int qtile = slot % 5;

    __shared__ char lds[49152];           // [2 buf][Q 16KB | D 8KB]
    __shared__ int thrS[QB2];

    const int tid = (int)threadIdx.x;
    const int ln = tid & 63;
    const int wv = tid >> 6;              // 0..7
    const int wr = wv >> 1;               // 0..3 (q quarter)
    const int wc = wv & 1;                // 0..1 (n half)
    const int q0 = qtile * QB2;
    const int n0 = chunk * NB;

    if (tid < QB2) thrS[tid] = thrI[q0 + tid];

    i32x4 acc[4][4] = {};

    auto stageQ = [&](int kc, int buf) {
#pragma unroll
        for (int c = 0; c < 2; ++c) {
            const int U = c * 512 + tid;             // 1024 units (16 KB)
            const int r = U >> 2;                    // 0..255
            const int u = (U & 3) ^ ((r >> 1) & 3);
            gload_lds16(Qb + (size_t)(q0 + r) * ND + kc + u * 16,
                        lds + buf * 24576 + U * 16);
        }
    };
    auto stageD = [&](int kc, int buf) {
        const int U = tid;                           // 512 units (8 KB)
        const int r = U >> 2;                        // 0..127
        const int u = (U & 3) ^ ((r >> 1) & 3);
        gload_lds16(Db + (size_t)(n0 + r) * ND + kc + u * 16,
                    lds + buf * 24576 + 16384 + U * 16);
    };
    auto compute = [&](int buf) {
        const char* Qt = lds + buf * 24576;
        const char* Dt = Qt + 16384;
        i32x4 a[4], b[4];
#pragma unroll
        for (int qt = 0; qt < 4; ++qt) {
            const int r = wr * 64 + qt * 16 + (ln & 15);
            const int u = (ln >> 4) ^ ((r >> 1) & 3);
            a[qt] = *(const i32x4*)(Qt + r * 64 + u * 16);
        }
#pragma unroll
        for (int nt = 0; nt < 4; ++nt) {
            const int r = wc * 64 + nt * 16 + (ln & 15);
            const int u = (ln >> 4) ^ ((r >> 1) & 3);
            b[nt] = *(const i32x4*)(Dt + r * 64 + u * 16);
        }
        __builtin_amdgcn_s_setprio(1);
#pragma unroll
        for (int qt = 0; qt < 4; ++qt)
#pragma unroll
            for (int nt = 0; nt < 4; ++nt)
                acc[qt][nt] = __builtin_amdgcn_mfma_i32_16x16x64_i8(
                    a[qt], b[nt], acc[qt][nt], 0, 0, 0);
        __builtin_amdgcn_s_setprio(0);
    };

    __syncthreads();               // clean vmcnt slate
    stageQ(0, 0); stageD(0, 0);
    stageQ(KT, 1); stageD(KT, 1);
#pragma unroll
    for (int it = 0; it < NKIT; ++it) {
        if (it < NKIT - 1) PIPE_BAR(3); else PIPE_BAR(0);
        const int buf = it & 1;
        compute(buf);
        LGKM_BAR();
        if (it + 2 < NKIT) { stageQ((it + 2) * KT, buf); stageD((it + 2) * KT, buf); }
    }

    const int lg = ln >> 4;
    const int lc = ln & 15;
#pragma unroll
    for (int qt = 0; qt < 4; ++qt) {
#pragma unroll
        for (int c = 0; c < 4; ++c) {
            const int rloc = wr * 64 + qt * 16 + lg * 4 + c;
            const int row = q0 + rloc;
            const int T = thrS[rloc];
#pragma unroll
            for (int nt = 0; nt < 4; ++nt) {
                const int v = acc[qt][nt][c];
                if (v > T) {
                    const int n = n0 + wc * 64 + nt * 16 + lc;
                    if (n < NDB) {
                        const int slot2 = atomicAdd(&candCnt[row], 1);
                        if (slot2 < CAP) candId[(size_t)row * CAP + slot2] = n;
                    }
                }
            }
        }
    }
}

// ---------------------------------------------------------------------------
// Fallback (ws too small for dbi8): GEMM with in-register cvt (proven path).
// ---------------------------------------------------------------------------
__global__ __launch_bounds__(512) void gemm2_cvt_kernel(
    const signed char* __restrict__ Qb, const float* __restrict__ Df,
    const int* __restrict__ thrI, int* __restrict__ candCnt, int* __restrict__ candId,
    int qrows)
{
    __shared__ char lds[49152];
    __shared__ int thrS[QB2];
    const int tid = (int)threadIdx.x;
    const int ln = tid & 63;
    const int wv = tid >> 6;
    const int wr = wv >> 1;
    const int wc = wv & 1;
    const int q0 = blockIdx.x * QB2;
    const int n0 = blockIdx.y * NB;
    if (tid < QB2 && q0 + tid < qrows) thrS[tid] = thrI[q0 + tid];
    else if (tid < QB2) thrS[tid] = 0x7fffffff;

    i32x4 acc[4][4] = {};
    auto stageQ = [&](int kc, int buf) {
#pragma unroll
        for (int c = 0; c < 2; ++c) {
            const int U = c * 512 + tid;
            const int r = U >> 2;
            const int u = (U & 3) ^ ((r >> 1) & 3);
            const int gq = q0 + r;
            if (gq < qrows)
                gload_lds16(Qb + (size_t)gq * ND + kc + u * 16,
                            lds + buf * 24576 + U * 16);
            else
                *(i32x4*)(lds + buf * 24576 + U * 16) = i32x4{0, 0, 0, 0};
        }
    };
    auto stageDcvt = [&](int kc, int buf) {
        const int U = tid;
        const int r = U >> 2;
        const int u = (U & 3) ^ ((r >> 1) & 3);
        const int gn = n0 + r;
        union { signed char cc[16]; i32x4 v; } w;
        if (gn < NDB) {
#pragma unroll
            for (int j = 0; j < 4; ++j) {
                const float4 f = *(const float4*)(Df + (size_t)gn * ND + kc + u * 16 + j * 4);
                w.cc[j * 4 + 0] = f2i8(f.x);
                w.cc[j * 4 + 1] = f2i8(f.y);
                w.cc[j * 4 + 2] = f2i8(f.z);
                w.cc[j * 4 + 3] = f2i8(f.w);
            }
        } else {
#pragma unroll
            for (int j = 0; j < 16; ++j) w.cc[j] = 0;
        }
        *(i32x4*)(lds + buf * 24576 + 16384 + U * 16) = w.v;
    };
    stageQ(0, 0); stageDcvt(0, 0);
    for (int it = 0; it < NKIT; ++it) {
        const int buf = it & 1;
        __syncthreads();
        if (it + 1 < NKIT) { stageQ((it + 1) * KT, buf ^ 1); stageDcvt((it + 1) * KT, buf ^ 1); }
        const char* Qt = lds + buf * 24576;
        const char* Dt = Qt + 16384;
        i32x4 a[4], b[4];
#pragma unroll
        for (int qt = 0; qt < 4; ++qt) {
            const int r = wr * 64 + qt * 16 + (ln & 15);
            const int u = (ln >> 4) ^ ((r >> 1) & 3);
            a[qt] = *(const i32x4*)(Qt + r * 64 + u * 16);
        }
#pragma unroll
        for (int nt = 0; nt < 4; ++nt) {
            const int r = wc * 64 + nt * 16 + (ln & 15);
            const int u = (ln >> 4) ^ ((r >> 1) & 3);
            b[nt] = *(const i32x4*)(Dt + r * 64 + u * 16);
        }
#pragma unroll
        for (int qt = 0; qt < 4; ++qt)
#pragma unroll
            for (int nt = 0; nt < 4; ++nt)
                acc[qt][nt] = __builtin_amdgcn_mfma_i32_16x16x64_i8(
                    a[qt], b[nt], acc[qt][nt], 0, 0, 0);
        __syncthreads();
    }
    const int lg = ln >> 4;
    const int lc = ln & 15;
#pragma unroll
    for (int qt = 0; qt < 4; ++qt) {
#pragma unroll
        for (int c = 0; c < 4; ++c) {
            const int rloc = wr * 64 + qt * 16 + lg * 4 + c;
            const int row = q0 + rloc;
            if (row >= qrows) continue;
            const int T = thrS[rloc];
#pragma unroll
            for (int nt = 0; nt < 4; ++nt) {
                const int v = acc[qt][nt][c];
                if (v > T) {
                    const int n = n0 + wc * 64 + nt * 16 + lc;
                    if (n < NDB) {
                        const int slot = atomicAdd(&candCnt[row], 1);
                        if (slot < CAP) candId[(size_t)row * CAP + slot] = n;
                    }
                }
            }
        }
    }
}

// ---------------------------------------------------------------------------
// Candidate rescore helper: 2 candidates per wave per iteration (ILP).
// ---------------------------------------------------------------------------
__device__ __forceinline__ void rescore_cands(
    const float* __restrict__ db, const int* __restrict__ candId,
    size_t base, int nc, int wv, int ln,
    const float* qs, float* sc, int* sid)
{
    const float4 qa = *(const float4*)&qs[ln * 8];
    const float4 qb = *(const float4*)&qs[ln * 8 + 4];
    for (int i0 = wv * 2; i0 < nc; i0 += 8) {
        const int i1 = i0 + 1;
        const bool has1 = (i1 < nc);
        const int idA = candId[base + i0];
        const int idB = has1 ? candId[base + i1] : idA;
        const float4* dA = (const float4*)(db + (size_t)idA * ND);
        const float4* dB = (const float4*)(db + (size_t)idB * ND);
        const float4 a0 = dA[ln * 2];
        const float4 a1 = dA[ln * 2 + 1];
        const float4 b0 = dB[ln * 2];
        const float4 b1 = dB[ln * 2 + 1];
        float sA = qa.x * a0.x + qa.y * a0.y + qa.z * a0.z + qa.w * a0.w
                 + qb.x * a1.x + qb.y * a1.y + qb.z * a1.z + qb.w * a1.w;
        float sB = qa.x * b0.x + qa.y * b0.y + qa.z * b0.z + qa.w * b0.w
                 + qb.x * b1.x + qb.y * b1.y + qb.z * b1.z + qb.w * b1.w;
        for (int off = 32; off; off >>= 1) {
            sA += __shfl_xor(sA, off);
            sB += __shfl_xor(sB, off);
        }
        if (ln == 0) {
            sc[i0] = sA; sid[i0] = idA;
            if (has1) { sc[i1] = sB; sid[i1] = idB; }
        }
    }
}

// ---------------------------------------------------------------------------
// Stage-1 rescore (exact fp32 top-10) FUSED with gather/query_top_k/stage-2
// prep: writes s1I, q2i8, qtk, thrI2 (Z2), zeroes cnt2. One block/query.
// ---------------------------------------------------------------------------
__global__ __launch_bounds__(256) void rescore_fuse_kernel(
    const float* __restrict__ Qf,            // [NQ][512]
    const float* __restrict__ db,            // [NDB][512]
    const int* __restrict__ candCnt, const int* __restrict__ candId,
    int* __restrict__ s1I,
    signed char* __restrict__ q2i8,
    float* __restrict__ qtk,
    int* __restrict__ thrI2, int* __restrict__ cnt2)
{
    const int b = blockIdx.x;
    const int tid = (int)threadIdx.x;
    const int ln = tid & 63;
    const int wv = tid >> 6;

    __shared__ float qs[ND];
    __shared__ float sc[CAP];
    __shared__ int   sid[CAP];
    __shared__ float rbs[4];
    __shared__ int   rbi[4], rbsl[4];
    __shared__ int   topI[MM];
    __shared__ float red[11][4];

    qs[tid] = Qf[(size_t)b * ND + tid];
    qs[tid + 256] = Qf[(size_t)b * ND + tid + 256];
    const int nc = min(candCnt[b], CAP);
    for (int i = tid; i < CAP; i += 256) { sc[i] = -INFINITY; sid[i] = 0x7fffffff; }
    __syncthreads();

    rescore_cands(db, candId, (size_t)b * CAP, nc, wv, ln, qs, sc, sid);
    __syncthreads();

    for (int it = 0; it < KK; ++it) {
        float bs = -INFINITY;
        int bid = 0x7fffffff, bsl = -1;
        for (int i = tid; i < nc; i += 256) {
            const float s = sc[i];
            if (s > bs || (s == bs && sid[i] < bid)) { bs = s; bid = sid[i]; bsl = i; }
        }
        for (int off = 32; off; off >>= 1) {
            const float os = __shfl_xor(bs, off);
            const int oi = __shfl_xor(bid, off);
            const int osl = __shfl_xor(bsl, off);
            if (os > bs || (os == bs && oi < bid)) { bs = os; bid = oi; bsl = osl; }
        }
        if (ln == 0) { rbs[wv] = bs; rbi[wv] = bid; rbsl[wv] = bsl; }
        __syncthreads();
        if (tid == 0) {
            float fb = -INFINITY; int fi = 0x7fffffff, fs = -1;
#pragma unroll
            for (int w = 0; w < 4; ++w) {
                if (rbs[w] > fb || (rbs[w] == fb && rbi[w] < fi)) {
                    fb = rbs[w]; fi = rbi[w]; fs = rbsl[w];
                }
            }
            const int idw = (fi == 0x7fffffff) ? 0 : fi;
            s1I[b * MM + it] = idw;
            topI[it] = idw;
            if (fs >= 0) sc[fs] = -INFINITY;
        }
        __syncthreads();
    }

    // ---- phase 2: gather top_m, qtk, q2 prep ----
    const float q0v = qs[tid];
    const float q1v = qs[tid + 256];
    float mx0 = q0v, mx1 = q1v;
    float ssq[MM];
#pragma unroll
    for (int m = 0; m < MM; ++m) {
        const int id = topI[m];
        const float v0 = db[(size_t)id * ND + tid];
        const float v1 = db[(size_t)id * ND + tid + 256];
        const size_t rowo = (size_t)(b * MM + m) * ND;
        q2i8[rowo + tid] = f2i8(v0);
        q2i8[rowo + tid + 256] = f2i8(v1);
        ssq[m] = v0 * v0 + v1 * v1;
        if (m < KK - 1) { mx0 = fmaxf(mx0, v0); mx1 = fmaxf(mx1, v1); }
    }
    float sqq = mx0 * mx0 + mx1 * mx1;
#pragma unroll
    for (int m = 0; m < MM; ++m) {
        float s = ssq[m];
        for (int off = 32; off; off >>= 1) s += __shfl_xor(s, off);
        if (ln == 0) red[m][wv] = s;
    }
    for (int off = 32; off; off >>= 1) sqq += __shfl_xor(sqq, off);
    if (ln == 0) red[10][wv] = sqq;
    __syncthreads();
    if (tid < MM) {
        const float tot = red[tid][0] + red[tid][1] + red[tid][2] + red[tid][3];
        thrI2[b * MM + tid] = (int)(QSC * QSC * Z2 * sqrtf(tot));
        cnt2[b * MM + tid] = 0;
    }
    const float tq = red[10][0] + red[10][1] + red[10][2] + red[10][3];
    const float inv = 1.0f / fmaxf(sqrtf(tq), 1e-12f);
    qtk[(size_t)b * ND + tid] = mx0 * inv;
    qtk[(size_t)b * ND + tid + 256] = mx1 * inv;
}

// ---------------------------------------------------------------------------
// Stage-2 exact fp32 rescore + top-10 FUSED with refinement + final score.
// One block per (b, m) row; stage-2 query row read via s1I indirection.
// ---------------------------------------------------------------------------
__global__ __launch_bounds__(256) void rescore_refine_kernel(
    const int* __restrict__ s1I,             // [NQ*MM] stage-2 query db-ids
    const float* __restrict__ q,             // [NQ][512] original queries
    const float* __restrict__ qtk,           // [NQ][512] normalized query_top_k
    const float* __restrict__ db,
    const int* __restrict__ candCnt, const int* __restrict__ candId,
    float* __restrict__ finalS)
{
    const int row = blockIdx.x;              // b*MM + m
    const int b = row / MM;
    const int tid = (int)threadIdx.x;
    const int ln = tid & 63;
    const int wv = tid >> 6;

    __shared__ float qs[ND];
    __shared__ float sc[CAP];
    __shared__ int   sid[CAP];
    __shared__ float rbs[4];
    __shared__ int   rbi[4], rbsl[4];
    __shared__ float topS[KK];
    __shared__ int   topI[KK];
    __shared__ float red[3][4];

    const int qid = s1I[row];                // stage-2 query = db[qid]
    qs[tid] = db[(size_t)qid * ND + tid];
    qs[tid + 256] = db[(size_t)qid * ND + tid + 256];
    const int nc = min(candCnt[row], CAP);
    for (int i = tid; i < CAP; i += 256) { sc[i] = -INFINITY; sid[i] = 0x7fffffff; }
    __syncthreads();

    rescore_cands(db, candId, (size_t)row * CAP, nc, wv, ln, qs, sc, sid);
    __syncthreads();

    for (int it = 0; it < KK; ++it) {
        float bs = -INFINITY;
        int bid = 0x7fffffff, bsl = -1;
        for (int i = tid; i < nc; i += 256) {
            const float s = sc[i];
            if (s > bs || (s == bs && sid[i] < bid)) { bs = s; bid = sid[i]; bsl = i; }
        }
        for (int off = 32; off; off >>= 1) {
            const float os = __shfl_xor(bs, off);
            const int oi = __shfl_xor(bid, off);
            const int osl = __shfl_xor(bsl, off);
            if (os > bs || (os == bs && oi < bid)) { bs = os; bid = oi; bsl = osl; }
        }
        if (ln == 0) { rbs[wv] = bs; rbi[wv] = bid; rbsl[wv] = bsl; }
        __syncthreads();
        if (tid == 0) {
            float fb = -INFINITY; int fi = 0x7fffffff, fs = -1;
#pragma unroll
            for (int w = 0; w < 4; ++w) {
                if (rbs[w] > fb || (rbs[w] == fb && rbi[w] < fi)) {
                    fb = rbs[w]; fi = rbi[w]; fs = rbsl[w];
                }
            }
            if (!(fb > -INFINITY)) { fb = 0.f; fi = 0; }
            topS[it] = fb;
            topI[it] = (fi == 0x7fffffff) ? 0 : fi;
            if (fs >= 0) sc[fs] = -INFINITY;
        }
        __syncthreads();
    }

    // ---- refinement phase, top-10 rows L2-hot ----
    float ssum = 0.f;
#pragma unroll
    for (int m = 0; m < KK; ++m) ssum += topS[m];
    const float nf = 3.f + 2.f * ssum;

    const float q0v = q[(size_t)b * ND + tid];
    const float q1v = q[(size_t)b * ND + tid + 256];
    float w0 = 2.f * q0v;
    float w1 = 2.f * q1v;
#pragma unroll
    for (int m = 0; m < KK; ++m) {
        const int id = topI[m];
        const float w = 2.f * topS[m];
        w0 = fmaf(w, db[(size_t)id * ND + tid], w0);
        w1 = fmaf(w, db[(size_t)id * ND + tid + 256], w1);
    }
    w0 /= nf;
    w1 /= nf;

    float s_n = w0 * w0 + w1 * w1;
    float s_1 = w0 * q0v + w1 * q1v;
    float s_2 = w0 * qtk[(size_t)b * ND + tid] + w1 * qtk[(size_t)b * ND + tid + 256];
    for (int off = 32; off; off >>= 1) {
        s_n += __shfl_xor(s_n, off);
        s_1 += __shfl_xor(s_1, off);
        s_2 += __shfl_xor(s_2, off);
    }
    if (ln == 0) { red[0][wv] = s_n; red[1][wv] = s_1; red[2][wv] = s_2; }
    __syncthreads();
    if (tid == 0) {
        const float tn = red[0][0] + red[0][1] + red[0][2] + red[0][3];
        const float t1 = red[1][0] + red[1][1] + red[1][2] + red[1][3];
        const float t2 = red[2][0] + red[2][1] + red[2][2] + red[2][3];
        const float inv = 1.0f / fmaxf(sqrtf(tn), 1e-12f);
        finalS[row] = 0.5f * (t1 * inv + t2 * inv);
    }
}

// ---------------------------------------------------------------------------
// Final top-3 of 10 per query; ids (as float) then scores.
// ---------------------------------------------------------------------------
__global__ __launch_bounds__(64) void final_topk_kernel(
    const float* __restrict__ finalS, const int* __restrict__ s1I,
    float* __restrict__ out)
{
    const int b = blockIdx.x * 64 + (int)threadIdx.x;
    if (b >= NQ) return;
    float s[MM];
#pragma unroll
    for (int m = 0; m < MM; ++m) s[m] = finalS[b * MM + m];
#pragma unroll
    for (int x = 0; x < TOPX; ++x) {
        float bs = -INFINITY;
        int bm = 0;
#pragma unroll
        for (int m = 0; m < MM; ++m) {
            if (s[m] > bs) { bs = s[m]; bm = m; }
        }
        out[b * TOPX + x] = (float)s1I[b * MM + bm];
        out[NQ * TOPX + b * TOPX + x] = bs;
        s[bm] = -INFINITY;
    }
}

// ---------------------------------------------------------------------------
extern "C" void kernel_launch(void* const* d_in, const int* in_sizes, int n_in,
                              void* d_out, int out_size, void* d_ws, size_t ws_size,
                              hipStream_t stream)
{
    const float* q = (const float*)d_in[0];
    const float* db = (const float*)d_in[1];
    float* out = (float*)d_out;

    char* ws = (char*)d_ws;
    size_t off = 0;
    auto alloc = [&](size_t bytes) -> void* {
        void* p = ws + off;
        off += (bytes + 255) & ~(size_t)255;
        return p;
    };
    signed char* qi8  = (signed char*)alloc((size_t)NQ * ND);
    signed char* q2i8 = (signed char*)alloc((size_t)R2 * ND);
    float* qtk  = (float*)alloc(sizeof(float) * NQ * ND);
    int*   thrI = (int*)alloc(sizeof(int) * NROWT);
    int*   cnt  = (int*)alloc(sizeof(int) * NROWT);
    int*   cid  = (int*)alloc(sizeof(int) * (size_t)NROWT * CAP);
    int*   s1I  = (int*)alloc(sizeof(int) * NQ * MM);
    float* fS   = (float*)alloc(sizeof(float) * NQ * MM);
    signed char* dbi8 = (signed char*)alloc((size_t)NDBP * ND);   // 51.25 MB
    const bool pathA = (ws_size >= off);

    // Stage-1 prep (quantize queries, thresholds, zero cnt rows 0..NQ)
    prep_q_kernel<<<NQ, 256, 0, stream>>>(q, qi8, thrI, cnt);

    if (pathA) {
        // Fused: per-chunk cvt with ALL loads before ANY store (store-gating
        // fix) -> global dbi8 -> 2-barrier GEMM readback (L2-hot).
        gemm1c_kernel<<<NCH1, 256, 0, stream>>>(qi8, db, dbi8, thrI, cnt, cid);
    } else {
        gemm2_cvt_kernel<<<dim3(1, NCHUNK), 512, 0, stream>>>(
            qi8, db, thrI, cnt, cid, NQ);
    }

    // Stage-1 exact rescore fused with gather/qtk/stage-2 prep
    rescore_fuse_kernel<<<NQ, 256, 0, stream>>>(
        q, db, cnt, cid, s1I, q2i8, qtk, thrI + NQ, cnt + NQ);

    // Stage 2: candidates (pipelined i8 GEMM, XCD-grouped)
    if (pathA)
        gemm2s_kernel<<<3920, 512, 0, stream>>>(
            q2i8, dbi8, thrI + NQ, cnt + NQ, cid + (size_t)NQ * CAP);
    else
        gemm2_cvt_kernel<<<dim3(R2 / QB2, NCHUNK), 512, 0, stream>>>(
            q2i8, db, thrI + NQ, cnt + NQ, cid + (size_t)NQ * CAP, R2);

    // Stage-2 exact rescore + refinement + final scores (fused)
    rescore_refine_kernel<<<R2, 256, 0, stream>>>(
        s1I, q, qtk, db, cnt + NQ, cid + (size_t)NQ * CAP, fS);

    // Final top-3 -> output
    final_topk_kernel<<<(NQ + 63) / 64, 64, 0, stream>>>(fS, s1I, out);
    (void)in_sizes; (void)n_in; (void)out_size;
}

// Round 19
// 213.787 us; speedup vs baseline: 1.0365x; 1.0365x over previous
//
#include <hip/hip_runtime.h>
#include <math.h>

// Problem constants
#define NQ    128
#define ND    512
#define NDB   100000
#define NDBP  100096            // padded to multiple of 128
#define MM    10
#define KK    10
#define TOPX  3
#define R2    (NQ * MM)         // 1280

// GEMM tiling
#define QB1    128              // stage-1 q rows per block
#define NB1    64               // stage-1 db rows per block
#define NCH1   (NDBP / NB1)     // 1564
#define QB2    256              // stage-2 q rows per block
#define NB     128              // stage-2 db rows per block
#define KT     64               // K elems per stage chunk (one i8 MFMA K-step)
#define NKIT   (ND / KT)        // 8
#define NCHUNK (NDBP / NB)      // 782

// Candidate filtering
#define Z0    3.125f            // stage-1 threshold = Z0 * ||row||
#define Z2    3.3f              // stage-2 threshold (10th-best ~ 4.29||q||)
#define QSC   32.0f             // i8 quantization scale
#define CAP   384               // max candidates per row
#define NROWT (NQ + R2)         // 1408 rows with thresholds

typedef int i32x4 __attribute__((ext_vector_type(4)));

// counted-vmcnt pipeline barrier: wait + barrier fused in one asm so nothing
// can be scheduled between; memory clobber pins all LDS/global ops.
#define PIPE_BAR(VM) asm volatile("s_waitcnt vmcnt(" #VM ")\n\ts_barrier" ::: "memory")
#define LGKM_BAR()   asm volatile("s_waitcnt lgkmcnt(0)\n\ts_barrier" ::: "memory")

__device__ __forceinline__ void gload_lds16(const void* gsrc, void* ldst) {
    __builtin_amdgcn_global_load_lds(
        (const __attribute__((address_space(1))) unsigned int*)gsrc,
        (__attribute__((address_space(3))) unsigned int*)ldst, 16, 0, 0);
}

__device__ __forceinline__ signed char f2i8(float x) {
    int v = (int)rintf(x * QSC);
    v = v > 127 ? 127 : v;
    v = v < -127 ? -127 : v;
    return (signed char)v;
}

// ---------------------------------------------------------------------------
// Stage-1 query prep: quantize to i8, integer threshold, zero cnt row.
// ---------------------------------------------------------------------------
__global__ __launch_bounds__(256) void prep_q_kernel(
    const float* __restrict__ src, signed char* __restrict__ dst,
    int* __restrict__ thrI, int* __restrict__ cnt)
{
    const int row = blockIdx.x;
    const int t = (int)threadIdx.x;
    __shared__ float red[4];
    const float a = src[(size_t)row * ND + t];
    const float b = src[(size_t)row * ND + t + 256];
    dst[(size_t)row * ND + t] = f2i8(a);
    dst[(size_t)row * ND + t + 256] = f2i8(b);
    float ss = a * a + b * b;
    for (int off = 32; off; off >>= 1) ss += __shfl_xor(ss, off);
    if ((t & 63) == 0) red[t >> 6] = ss;
    __syncthreads();
    if (t == 0) {
        const float tot = red[0] + red[1] + red[2] + red[3];
        thrI[row] = (int)(QSC * QSC * Z0 * sqrtf(tot));
        cnt[row] = 0;
    }
}

// ---------------------------------------------------------------------------
// Stage-1 FUSED cvt+GEMM (pathA) = r17 best config + NON-TEMPORAL dbi8
// stores (stop the 51MB dbi8 stream evicting the 205MB f32 set from L3;
// f32+dbi8 = 256MB = exactly L3 capacity -> thrash without nt).
//   phase 1: dense streaming f32->i8, 3-deep register pipeline.
//   barrier: __syncthreads drains vmcnt -> stores visible (coherent path).
//   phase 2: PIPE_BAR(3) pipelined GEMM reading chunk back via
//            global_load_lds. LDS 24 KB.
// ---------------------------------------------------------------------------
__global__ __launch_bounds__(256) void gemm1c_kernel(
    const signed char* __restrict__ Qb,   // [NQ][512] i8
    const float* __restrict__ Df,         // [NDB][512] f32
    signed char* __restrict__ DbOut,      // [NDBP][512] i8 out
    const int* __restrict__ thrI,
    int* __restrict__ candCnt, int* __restrict__ candId)
{
    __shared__ char lds[24576];           // [2 buf][Q 8KB | D 4KB]
    __shared__ int thrS[QB1];

    const int tid = (int)threadIdx.x;
    const int ln = tid & 63;
    const int wv = tid >> 6;
    const int wr = wv >> 1;               // 0..1 (q half of 128)
    const int wc = wv & 1;                // 0..1 (n half of 64)
    const int n0 = blockIdx.x * NB1;

    if (tid < QB1) thrS[tid] = thrI[tid];

    // ---- phase 1: own-chunk cvt, 8 iters x 16 i8/thread, 3-deep pipeline ----
    {
        const size_t base = (size_t)n0 * ND;
        const size_t lim = (size_t)NDB * ND;
        float4 f[3][4];
        bool ok[3];
#pragma unroll
        for (int pp = 0; pp < 3; ++pp) {   // prologue: load iters 0..2
            const size_t o = base + (size_t)pp * 4096 + (size_t)tid * 16;
            ok[pp] = (o + 16 <= lim);
            const float4* p = (const float4*)(Df + (ok[pp] ? o : 0));
#pragma unroll
            for (int j = 0; j < 4; ++j) f[pp][j] = p[j];
        }
#pragma unroll
        for (int it = 0; it < 8; ++it) {
            const int cur = it % 3;        // compile-time after full unroll
            union { signed char c[16]; i32x4 v; } u;
            if (ok[cur]) {
#pragma unroll
                for (int j = 0; j < 4; ++j) {
                    u.c[j * 4 + 0] = f2i8(f[cur][j].x);
                    u.c[j * 4 + 1] = f2i8(f[cur][j].y);
                    u.c[j * 4 + 2] = f2i8(f[cur][j].z);
                    u.c[j * 4 + 3] = f2i8(f[cur][j].w);
                }
            } else {
#pragma unroll
                for (int j = 0; j < 16; ++j) u.c[j] = 0;
            }
            // NT store: minimal cache retention -> doesn't evict f32 L3 set
            __builtin_nontemporal_store(
                u.v, (i32x4*)(DbOut + base + (size_t)it * 4096 + (size_t)tid * 16));
            if (it + 3 < 8) {              // reload slot for iter it+3
                const size_t o = base + (size_t)(it + 3) * 4096 + (size_t)tid * 16;
                ok[cur] = (o + 16 <= lim);
                const float4* p = (const float4*)(Df + (ok[cur] ? o : 0));
#pragma unroll
                for (int j = 0; j < 4; ++j) f[cur][j] = p[j];
            }
        }
    }
    __syncthreads();   // drains vmcnt(0): stores visible (coherent)

    i32x4 acc[4][2] = {};

    auto stageQ = [&](int kc, int buf) {
#pragma unroll
        for (int c = 0; c < 2; ++c) {
            const int U = c * 256 + tid;               // 512 units (8 KB)
            const int r = U >> 2;                      // 0..127
            const int u = (U & 3) ^ ((r >> 1) & 3);
            gload_lds16(Qb + (size_t)r * ND + kc + u * 16,
                        lds + buf * 12288 + U * 16);
        }
    };
    auto stageD = [&](int kc, int buf) {
        const int U = tid;                             // 256 units (4 KB)
        const int r = U >> 2;                          // 0..63
        const int u = (U & 3) ^ ((r >> 1) & 3);
        gload_lds16(DbOut + (size_t)(n0 + r) * ND + kc + u * 16,
                    lds + buf * 12288 + 8192 + U * 16);
    };
    auto compute = [&](int buf) {
        const char* Qt = lds + buf * 12288;
        const char* Dt = Qt + 8192;
        i32x4 a[4], b[2];
#pragma unroll
        for (int qt = 0; qt < 4; ++qt) {
            const int r = wr * 64 + qt * 16 + (ln & 15);
            const int u = (ln >> 4) ^ ((r >> 1) & 3);
            a[qt] = *(const i32x4*)(Qt + r * 64 + u * 16);
        }
#pragma unroll
        for (int nt = 0; nt < 2; ++nt) {
            const int r = wc * 32 + nt * 16 + (ln & 15);
            const int u = (ln >> 4) ^ ((r >> 1) & 3);
            b[nt] = *(const i32x4*)(Dt + r * 64 + u * 16);
        }
        __builtin_amdgcn_s_setprio(1);
#pragma unroll
        for (int qt = 0; qt < 4; ++qt)
#pragma unroll
            for (int nt = 0; nt < 2; ++nt)
                acc[qt][nt] = __builtin_amdgcn_mfma_i32_16x16x64_i8(
                    a[qt], b[nt], acc[qt][nt], 0, 0, 0);
        __builtin_amdgcn_s_setprio(0);
    };

    stageQ(0, 0); stageD(0, 0);
    stageQ(KT, 1); stageD(KT, 1);
#pragma unroll
    for (int it = 0; it < NKIT; ++it) {
        if (it < NKIT - 1) PIPE_BAR(3); else PIPE_BAR(0);
        const int buf = it & 1;
        compute(buf);
        LGKM_BAR();
        if (it + 2 < NKIT) { stageQ((it + 2) * KT, buf); stageD((it + 2) * KT, buf); }
    }

    // Threshold filter. C/D layout: col=lane&15, row=(lane>>4)*4+reg.
    const int lg = ln >> 4;
    const int lc = ln & 15;
#pragma unroll
    for (int qt = 0; qt < 4; ++qt) {
#pragma unroll
        for (int c = 0; c < 4; ++c) {
            const int rloc = wr * 64 + qt * 16 + lg * 4 + c;
            const int T = thrS[rloc];
#pragma unroll
            for (int nt = 0; nt < 2; ++nt) {
                const int v = acc[qt][nt][c];
                if (v > T) {
                    const int n = n0 + wc * 32 + nt * 16 + lc;
                    if (n < NDB) {
                        const int slot = atomicAdd(&candCnt[rloc], 1);
                        if (slot < CAP) candId[(size_t)rloc * CAP + slot] = n;
                    }
                }
            }
        }
    }
}

// ---------------------------------------------------------------------------
// Stage-2 GEMM (pathA): XCD-aware chunk grouping (round-8 proven winner).
// Flat grid 3920 (= 8 XCDs x 490 slots). Block 512 = 8 waves (4x2),
// per-wave 64x64, acc[4][4]. LDS 48KB, PIPE_BAR(3) pipeline.
// ---------------------------------------------------------------------------
__global__ __launch_bounds__(512) void gemm2s_kernel(
    const signed char* __restrict__ Qb,   // [R2][512] i8
    const signed char* __restrict__ Db,   // [NDBP][512] i8
    const int* __restrict__ thrI,
    int* __restrict__ candCnt, int* __restrict__ candId)
{
    const int bid = (int)blockIdx.x;
    const int xcd = bid & 7;
    const int slot = bid >> 3;                       // 0..489
    const int nch_x = (xcd < 6) ? 98 : 97;
    if (slot >= nch_x * 5) return;
    const int cstart = (xcd < 6) ? 98 * xcd : 98 * 6 + 97 * (xcd - 6);
    const int chunk = cstart + slot / 5;
    const int qtile = slot % 5;

    __shared__ char lds[49152];           // [2 buf][Q 16KB | D 8KB]
    __shared__ int thrS[QB2];

    const int tid = (int)threadIdx.x;
    const int ln = tid & 63;
    const int wv = tid >> 6;              // 0..7
    const int wr = wv >> 1;               // 0..3 (q quarter)
    const int wc = wv & 1;                // 0..1 (n half)
    const int q0 = qtile * QB2;
    const int n0 = chunk * NB;

    if (tid < QB2) thrS[tid] = thrI[q0 + tid];

    i32x4 acc[4][4] = {};

    auto stageQ = [&](int kc, int buf) {
#pragma unroll
        for (int c = 0; c < 2; ++c) {
            const int U = c * 512 + tid;             // 1024 units (16 KB)
            const int r = U >> 2;                    // 0..255
            const int u = (U & 3) ^ ((r >> 1) & 3);
            gload_lds16(Qb + (size_t)(q0 + r) * ND + kc + u * 16,
                        lds + buf * 24576 + U * 16);
        }
    };
    auto stageD = [&](int kc, int buf) {
        const int U = tid;                           // 512 units (8 KB)
        const int r = U >> 2;                        // 0..127
        const int u = (U & 3) ^ ((r >> 1) & 3);
        gload_lds16(Db + (size_t)(n0 + r) * ND + kc + u * 16,
                    lds + buf * 24576 + 16384 + U * 16);
    };
    auto compute = [&](int buf) {
        const char* Qt = lds + buf * 24576;
        const char* Dt = Qt + 16384;
        i32x4 a[4], b[4];
#pragma unroll
        for (int qt = 0; qt < 4; ++qt) {
            const int r = wr * 64 + qt * 16 + (ln & 15);
            const int u = (ln >> 4) ^ ((r >> 1) & 3);
            a[qt] = *(const i32x4*)(Qt + r * 64 + u * 16);
        }
#pragma unroll
        for (int nt = 0; nt < 4; ++nt) {
            const int r = wc * 64 + nt * 16 + (ln & 15);
            const int u = (ln >> 4) ^ ((r >> 1) & 3);
            b[nt] = *(const i32x4*)(Dt + r * 64 + u * 16);
        }
        __builtin_amdgcn_s_setprio(1);
#pragma unroll
        for (int qt = 0; qt < 4; ++qt)
#pragma unroll
            for (int nt = 0; nt < 4; ++nt)
                acc[qt][nt] = __builtin_amdgcn_mfma_i32_16x16x64_i8(
                    a[qt], b[nt], acc[qt][nt], 0, 0, 0);
        __builtin_amdgcn_s_setprio(0);
    };

    __syncthreads();               // clean vmcnt slate
    stageQ(0, 0); stageD(0, 0);
    stageQ(KT, 1); stageD(KT, 1);
#pragma unroll
    for (int it = 0; it < NKIT; ++it) {
        if (it < NKIT - 1) PIPE_BAR(3); else PIPE_BAR(0);
        const int buf = it & 1;
        compute(buf);
        LGKM_BAR();
        if (it + 2 < NKIT) { stageQ((it + 2) * KT, buf); stageD((it + 2) * KT, buf); }
    }

    const int lg = ln >> 4;
    const int lc = ln & 15;
#pragma unroll
    for (int qt = 0; qt < 4; ++qt) {
#pragma unroll
        for (int c = 0; c < 4; ++c) {
            const int rloc = wr * 64 + qt * 16 + lg * 4 + c;
            const int row = q0 + rloc;
            const int T = thrS[rloc];
#pragma unroll
            for (int nt = 0; nt < 4; ++nt) {
                const int v = acc[qt][nt][c];
                if (v > T) {
                    const int n = n0 + wc * 64 + nt * 16 + lc;
                    if (n < NDB) {
                        const int slot2 = atomicAdd(&candCnt[row], 1);
                        if (slot2 < CAP) candId[(size_t)row * CAP + slot2] = n;
                    }
                }
            }
        }
    }
}

// ---------------------------------------------------------------------------
// Fallback (ws too small for dbi8): GEMM with in-register cvt (proven path).
// ---------------------------------------------------------------------------
__global__ __launch_bounds__(512) void gemm2_cvt_kernel(
    const signed char* __restrict__ Qb, const float* __restrict__ Df,
    const int* __restrict__ thrI, int* __restrict__ candCnt, int* __restrict__ candId,
    int qrows)
{
    __shared__ char lds[49152];
    __shared__ int thrS[QB2];
    const int tid = (int)threadIdx.x;
    const int ln = tid & 63;
    const int wv = tid >> 6;
    const int wr = wv >> 1;
    const int wc = wv & 1;
    const int q0 = blockIdx.x * QB2;
    const int n0 = blockIdx.y * NB;
    if (tid < QB2 && q0 + tid < qrows) thrS[tid] = thrI[q0 + tid];
    else if (tid < QB2) thrS[tid] = 0x7fffffff;

    i32x4 acc[4][4] = {};
    auto stageQ = [&](int kc, int buf) {
#pragma unroll
        for (int c = 0; c < 2; ++c) {
            const int U = c * 512 + tid;
            const int r = U >> 2;
            const int u = (U & 3) ^ ((r >> 1) & 3);
            const int gq = q0 + r;
            if (gq < qrows)
                gload_lds16(Qb + (size_t)gq * ND + kc + u * 16,
                            lds + buf * 24576 + U * 16);
            else
                *(i32x4*)(lds + buf * 24576 + U * 16) = i32x4{0, 0, 0, 0};
        }
    };
    auto stageDcvt = [&](int kc, int buf) {
        const int U = tid;
        const int r = U >> 2;
        const int u = (U & 3) ^ ((r >> 1) & 3);
        const int gn = n0 + r;
        union { signed char cc[16]; i32x4 v; } w;
        if (gn < NDB) {
#pragma unroll
            for (int j = 0; j < 4; ++j) {
                const float4 f = *(const float4*)(Df + (size_t)gn * ND + kc + u * 16 + j * 4);
                w.cc[j * 4 + 0] = f2i8(f.x);
                w.cc[j * 4 + 1] = f2i8(f.y);
                w.cc[j * 4 + 2] = f2i8(f.z);
                w.cc[j * 4 + 3] = f2i8(f.w);
            }
        } else {
#pragma unroll
            for (int j = 0; j < 16; ++j) w.cc[j] = 0;
        }
        *(i32x4*)(lds + buf * 24576 + 16384 + U * 16) = w.v;
    };
    stageQ(0, 0); stageDcvt(0, 0);
    for (int it = 0; it < NKIT; ++it) {
        const int buf = it & 1;
        __syncthreads();
        if (it + 1 < NKIT) { stageQ((it + 1) * KT, buf ^ 1); stageDcvt((it + 1) * KT, buf ^ 1); }
        const char* Qt = lds + buf * 24576;
        const char* Dt = Qt + 16384;
        i32x4 a[4], b[4];
#pragma unroll
        for (int qt = 0; qt < 4; ++qt) {
            const int r = wr * 64 + qt * 16 + (ln & 15);
            const int u = (ln >> 4) ^ ((r >> 1) & 3);
            a[qt] = *(const i32x4*)(Qt + r * 64 + u * 16);
        }
#pragma unroll
        for (int nt = 0; nt < 4; ++nt) {
            const int r = wc * 64 + nt * 16 + (ln & 15);
            const int u = (ln >> 4) ^ ((r >> 1) & 3);
            b[nt] = *(const i32x4*)(Dt + r * 64 + u * 16);
        }
#pragma unroll
        for (int qt = 0; qt < 4; ++qt)
#pragma unroll
            for (int nt = 0; nt < 4; ++nt)
                acc[qt][nt] = __builtin_amdgcn_mfma_i32_16x16x64_i8(
                    a[qt], b[nt], acc[qt][nt], 0, 0, 0);
        __syncthreads();
    }
    const int lg = ln >> 4;
    const int lc = ln & 15;
#pragma unroll
    for (int qt = 0; qt < 4; ++qt) {
#pragma unroll
        for (int c = 0; c < 4; ++c) {
            const int rloc = wr * 64 + qt * 16 + lg * 4 + c;
            const int row = q0 + rloc;
            if (row >= qrows) continue;
            const int T = thrS[rloc];
#pragma unroll
            for (int nt = 0; nt < 4; ++nt) {
                const int v = acc[qt][nt][c];
                if (v > T) {
                    const int n = n0 + wc * 64 + nt * 16 + lc;
                    if (n < NDB) {
                        const int slot = atomicAdd(&candCnt[row], 1);
                        if (slot < CAP) candId[(size_t)row * CAP + slot] = n;
                    }
                }
            }
        }
    }
}

// ---------------------------------------------------------------------------
// Candidate rescore helper: 2 candidates per wave per iteration (ILP).
// ---------------------------------------------------------------------------
__device__ __forceinline__ void rescore_cands(
    const float* __restrict__ db, const int* __restrict__ candId,
    size_t base, int nc, int wv, int ln,
    const float* qs, float* sc, int* sid)
{
    const float4 qa = *(const float4*)&qs[ln * 8];
    const float4 qb = *(const float4*)&qs[ln * 8 + 4];
    for (int i0 = wv * 2; i0 < nc; i0 += 8) {
        const int i1 = i0 + 1;
        const bool has1 = (i1 < nc);
        const int idA = candId[base + i0];
        const int idB = has1 ? candId[base + i1] : idA;
        const float4* dA = (const float4*)(db + (size_t)idA * ND);
        const float4* dB = (const float4*)(db + (size_t)idB * ND);
        const float4 a0 = dA[ln * 2];
        const float4 a1 = dA[ln * 2 + 1];
        const float4 b0 = dB[ln * 2];
        const float4 b1 = dB[ln * 2 + 1];
        float sA = qa.x * a0.x + qa.y * a0.y + qa.z * a0.z + qa.w * a0.w
                 + qb.x * a1.x + qb.y * a1.y + qb.z * a1.z + qb.w * a1.w;
        float sB = qa.x * b0.x + qa.y * b0.y + qa.z * b0.z + qa.w * b0.w
                 + qb.x * b1.x + qb.y * b1.y + qb.z * b1.z + qb.w * b1.w;
        for (int off = 32; off; off >>= 1) {
            sA += __shfl_xor(sA, off);
            sB += __shfl_xor(sB, off);
        }
        if (ln == 0) {
            sc[i0] = sA; sid[i0] = idA;
            if (has1) { sc[i1] = sB; sid[i1] = idB; }
        }
    }
}

// ---------------------------------------------------------------------------
// Stage-1 rescore (exact fp32 top-10) FUSED with gather/query_top_k/stage-2
// prep: writes s1I, q2i8, qtk, thrI2 (Z2), zeroes cnt2. One block/query.
// ---------------------------------------------------------------------------
__global__ __launch_bounds__(256) void rescore_fuse_kernel(
    const float* __restrict__ Qf,            // [NQ][512]
    const float* __restrict__ db,            // [NDB][512]
    const int* __restrict__ candCnt, const int* __restrict__ candId,
    int* __restrict__ s1I,
    signed char* __restrict__ q2i8,
    float* __restrict__ qtk,
    int* __restrict__ thrI2, int* __restrict__ cnt2)
{
    const int b = blockIdx.x;
    const int tid = (int)threadIdx.x;
    const int ln = tid & 63;
    const int wv = tid >> 6;

    __shared__ float qs[ND];
    __shared__ float sc[CAP];
    __shared__ int   sid[CAP];
    __shared__ float rbs[4];
    __shared__ int   rbi[4], rbsl[4];
    __shared__ int   topI[MM];
    __shared__ float red[11][4];

    qs[tid] = Qf[(size_t)b * ND + tid];
    qs[tid + 256] = Qf[(size_t)b * ND + tid + 256];
    const int nc = min(candCnt[b], CAP);
    for (int i = tid; i < CAP; i += 256) { sc[i] = -INFINITY; sid[i] = 0x7fffffff; }
    __syncthreads();

    rescore_cands(db, candId, (size_t)b * CAP, nc, wv, ln, qs, sc, sid);
    __syncthreads();

    for (int it = 0; it < KK; ++it) {
        float bs = -INFINITY;
        int bid = 0x7fffffff, bsl = -1;
        for (int i = tid; i < nc; i += 256) {
            const float s = sc[i];
            if (s > bs || (s == bs && sid[i] < bid)) { bs = s; bid = sid[i]; bsl = i; }
        }
        for (int off = 32; off; off >>= 1) {
            const float os = __shfl_xor(bs, off);
            const int oi = __shfl_xor(bid, off);
            const int osl = __shfl_xor(bsl, off);
            if (os > bs || (os == bs && oi < bid)) { bs = os; bid = oi; bsl = osl; }
        }
        if (ln == 0) { rbs[wv] = bs; rbi[wv] = bid; rbsl[wv] = bsl; }
        __syncthreads();
        if (tid == 0) {
            float fb = -INFINITY; int fi = 0x7fffffff, fs = -1;
#pragma unroll
            for (int w = 0; w < 4; ++w) {
                if (rbs[w] > fb || (rbs[w] == fb && rbi[w] < fi)) {
                    fb = rbs[w]; fi = rbi[w]; fs = rbsl[w];
                }
            }
            const int idw = (fi == 0x7fffffff) ? 0 : fi;
            s1I[b * MM + it] = idw;
            topI[it] = idw;
            if (fs >= 0) sc[fs] = -INFINITY;
        }
        __syncthreads();
    }

    // ---- phase 2: gather top_m, qtk, q2 prep ----
    const float q0v = qs[tid];
    const float q1v = qs[tid + 256];
    float mx0 = q0v, mx1 = q1v;
    float ssq[MM];
#pragma unroll
    for (int m = 0; m < MM; ++m) {
        const int id = topI[m];
        const float v0 = db[(size_t)id * ND + tid];
        const float v1 = db[(size_t)id * ND + tid + 256];
        const size_t rowo = (size_t)(b * MM + m) * ND;
        q2i8[rowo + tid] = f2i8(v0);
        q2i8[rowo + tid + 256] = f2i8(v1);
        ssq[m] = v0 * v0 + v1 * v1;
        if (m < KK - 1) { mx0 = fmaxf(mx0, v0); mx1 = fmaxf(mx1, v1); }
    }
    float sqq = mx0 * mx0 + mx1 * mx1;
#pragma unroll
    for (int m = 0; m < MM; ++m) {
        float s = ssq[m];
        for (int off = 32; off; off >>= 1) s += __shfl_xor(s, off);
        if (ln == 0) red[m][wv] = s;
    }
    for (int off = 32; off; off >>= 1) sqq += __shfl_xor(sqq, off);
    if (ln == 0) red[10][wv] = sqq;
    __syncthreads();
    if (tid < MM) {
        const float tot = red[tid][0] + red[tid][1] + red[tid][2] + red[tid][3];
        thrI2[b * MM + tid] = (int)(QSC * QSC * Z2 * sqrtf(tot));
        cnt2[b * MM + tid] = 0;
    }
    const float tq = red[10][0] + red[10][1] + red[10][2] + red[10][3];
    const float inv = 1.0f / fmaxf(sqrtf(tq), 1e-12f);
    qtk[(size_t)b * ND + tid] = mx0 * inv;
    qtk[(size_t)b * ND + tid + 256] = mx1 * inv;
}

// ---------------------------------------------------------------------------
// Stage-2 exact fp32 rescore + top-10 FUSED with refinement + final score.
// One block per (b, m) row; stage-2 query row read via s1I indirection.
// ---------------------------------------------------------------------------
__global__ __launch_bounds__(256) void rescore_refine_kernel(
    const int* __restrict__ s1I,             // [NQ*MM] stage-2 query db-ids
    const float* __restrict__ q,             // [NQ][512] original queries
    const float* __restrict__ qtk,           // [NQ][512] normalized query_top_k
    const float* __restrict__ db,
    const int* __restrict__ candCnt, const int* __restrict__ candId,
    float* __restrict__ finalS)
{
    const int row = blockIdx.x;              // b*MM + m
    const int b = row / MM;
    const int tid = (int)threadIdx.x;
    const int ln = tid & 63;
    const int wv = tid >> 6;

    __shared__ float qs[ND];
    __shared__ float sc[CAP];
    __shared__ int   sid[CAP];
    __shared__ float rbs[4];
    __shared__ int   rbi[4], rbsl[4];
    __shared__ float topS[KK];
    __shared__ int   topI[KK];
    __shared__ float red[3][4];

    const int qid = s1I[row];                // stage-2 query = db[qid]
    qs[tid] = db[(size_t)qid * ND + tid];
    qs[tid + 256] = db[(size_t)qid * ND + tid + 256];
    const int nc = min(candCnt[row], CAP);
    for (int i = tid; i < CAP; i += 256) { sc[i] = -INFINITY; sid[i] = 0x7fffffff; }
    __syncthreads();

    rescore_cands(db, candId, (size_t)row * CAP, nc, wv, ln, qs, sc, sid);
    __syncthreads();

    for (int it = 0; it < KK; ++it) {
        float bs = -INFINITY;
        int bid = 0x7fffffff, bsl = -1;
        for (int i = tid; i < nc; i += 256) {
            const float s = sc[i];
            if (s > bs || (s == bs && sid[i] < bid)) { bs = s; bid = sid[i]; bsl = i; }
        }
        for (int off = 32; off; off >>= 1) {
            const float os = __shfl_xor(bs, off);
            const int oi = __shfl_xor(bid, off);
            const int osl = __shfl_xor(bsl, off);
            if (os > bs || (os == bs && oi < bid)) { bs = os; bid = oi; bsl = osl; }
        }
        if (ln == 0) { rbs[wv] = bs; rbi[wv] = bid; rbsl[wv] = bsl; }
        __syncthreads();
        if (tid == 0) {
            float fb = -INFINITY; int fi = 0x7fffffff, fs = -1;
#pragma unroll
            for (int w = 0; w < 4; ++w) {
                if (rbs[w] > fb || (rbs[w] == fb && rbi[w] < fi)) {
                    fb = rbs[w]; fi = rbi[w]; fs = rbsl[w];
                }
            }
            if (!(fb > -INFINITY)) { fb = 0.f; fi = 0; }
            topS[it] = fb;
            topI[it] = (fi == 0x7fffffff) ? 0 : fi;
            if (fs >= 0) sc[fs] = -INFINITY;
        }
        __syncthreads();
    }

    // ---- refinement phase, top-10 rows L2-hot ----
    float ssum = 0.f;
#pragma unroll
    for (int m = 0; m < KK; ++m) ssum += topS[m];
    const float nf = 3.f + 2.f * ssum;

    const float q0v = q[(size_t)b * ND + tid];
    const float q1v = q[(size_t)b * ND + tid + 256];
    float w0 = 2.f * q0v;
    float w1 = 2.f * q1v;
#pragma unroll
    for (int m = 0; m < KK; ++m) {
        const int id = topI[m];
        const float w = 2.f * topS[m];
        w0 = fmaf(w, db[(size_t)id * ND + tid], w0);
        w1 = fmaf(w, db[(size_t)id * ND + tid + 256], w1);
    }
    w0 /= nf;
    w1 /= nf;

    float s_n = w0 * w0 + w1 * w1;
    float s_1 = w0 * q0v + w1 * q1v;
    float s_2 = w0 * qtk[(size_t)b * ND + tid] + w1 * qtk[(size_t)b * ND + tid + 256];
    for (int off = 32; off; off >>= 1) {
        s_n += __shfl_xor(s_n, off);
        s_1 += __shfl_xor(s_1, off);
        s_2 += __shfl_xor(s_2, off);
    }
    if (ln == 0) { red[0][wv] = s_n; red[1][wv] = s_1; red[2][wv] = s_2; }
    __syncthreads();
    if (tid == 0) {
        const float tn = red[0][0] + red[0][1] + red[0][2] + red[0][3];
        const float t1 = red[1][0] + red[1][1] + red[1][2] + red[1][3];
        const float t2 = red[2][0] + red[2][1] + red[2][2] + red[2][3];
        const float inv = 1.0f / fmaxf(sqrtf(tn), 1e-12f);
        finalS[row] = 0.5f * (t1 * inv + t2 * inv);
    }
}

// ---------------------------------------------------------------------------
// Final top-3 of 10 per query; ids (as float) then scores.
// ---------------------------------------------------------------------------
__global__ __launch_bounds__(64) void final_topk_kernel(
    const float* __restrict__ finalS, const int* __restrict__ s1I,
    float* __restrict__ out)
{
    const int b = blockIdx.x * 64 + (int)threadIdx.x;
    if (b >= NQ) return;
    float s[MM];
#pragma unroll
    for (int m = 0; m < MM; ++m) s[m] = finalS[b * MM + m];
#pragma unroll
    for (int x = 0; x < TOPX; ++x) {
        float bs = -INFINITY;
        int bm = 0;
#pragma unroll
        for (int m = 0; m < MM; ++m) {
            if (s[m] > bs) { bs = s[m]; bm = m; }
        }
        out[b * TOPX + x] = (float)s1I[b * MM + bm];
        out[NQ * TOPX + b * TOPX + x] = bs;
        s[bm] = -INFINITY;
    }
}

// ---------------------------------------------------------------------------
extern "C" void kernel_launch(void* const* d_in, const int* in_sizes, int n_in,
                              void* d_out, int out_size, void* d_ws, size_t ws_size,
                              hipStream_t stream)
{
    const float* q = (const float*)d_in[0];
    const float* db = (const float*)d_in[1];
    float* out = (float*)d_out;

    char* ws = (char*)d_ws;
    size_t off = 0;
    auto alloc = [&](size_t bytes) -> void* {
        void* p = ws + off;
        off += (bytes + 255) & ~(size_t)255;
        return p;
    };
    signed char* qi8  = (signed char*)alloc((size_t)NQ * ND);
    signed char* q2i8 = (signed char*)alloc((size_t)R2 * ND);
    float* qtk  = (float*)alloc(sizeof(float) * NQ * ND);
    int*   thrI = (int*)alloc(sizeof(int) * NROWT);
    int*   cnt  = (int*)alloc(sizeof(int) * NROWT);
    int*   cid  = (int*)alloc(sizeof(int) * (size_t)NROWT * CAP);
    int*   s1I  = (int*)alloc(sizeof(int) * NQ * MM);
    float* fS   = (float*)alloc(sizeof(float) * NQ * MM);
    signed char* dbi8 = (signed char*)alloc((size_t)NDBP * ND);   // 51.25 MB
    const bool pathA = (ws_size >= off);

    // Stage-1 prep (quantize queries, thresholds, zero cnt rows 0..NQ)
    prep_q_kernel<<<NQ, 256, 0, stream>>>(q, qi8, thrI, cnt);

    if (pathA) {
        // Fused: per-chunk dense cvt (3-deep pipelined, NT dbi8 stores) ->
        // global dbi8 -> pipelined i8 GEMM readback.
        gemm1c_kernel<<<NCH1, 256, 0, stream>>>(qi8, db, dbi8, thrI, cnt, cid);
    } else {
        gemm2_cvt_kernel<<<dim3(1, NCHUNK), 512, 0, stream>>>(
            qi8, db, thrI, cnt, cid, NQ);
    }

    // Stage-1 exact rescore fused with gather/qtk/stage-2 prep
    rescore_fuse_kernel<<<NQ, 256, 0, stream>>>(
        q, db, cnt, cid, s1I, q2i8, qtk, thrI + NQ, cnt + NQ);

    // Stage 2: candidates (pipelined i8 GEMM, XCD-grouped)
    if (pathA)
        gemm2s_kernel<<<3920, 512, 0, stream>>>(
            q2i8, dbi8, thrI + NQ, cnt + NQ, cid + (size_t)NQ * CAP);
    else
        gemm2_cvt_kernel<<<dim3(R2 / QB2, NCHUNK), 512, 0, stream>>>(
            q2i8, db, thrI + NQ, cnt + NQ, cid + (size_t)NQ * CAP, R2);

    // Stage-2 exact rescore + refinement + final scores (fused)
    rescore_refine_kernel<<<R2, 256, 0, stream>>>(
        s1I, q, qtk, db, cnt + NQ, cid + (size_t)NQ * CAP, fS);

    // Final top-3 -> output
    final_topk_kernel<<<(NQ + 63) / 64, 64, 0, stream>>>(fS, s1I, out);
    (void)in_sizes; (void)n_in; (void)out_size;
}

// Round 20
// 211.085 us; speedup vs baseline: 1.0498x; 1.0128x over previous
//
#include <hip/hip_runtime.h>
#include <math.h>

// Problem constants
#define NQ    128
#define ND    512
#define NDB   100000
#define NDBP  100096            // padded to multiple of 128
#define MM    10
#define KK    10
#define TOPX  3
#define R2    (NQ * MM)         // 1280

// GEMM tiling
#define QB1    128              // stage-1 q rows per block
#define NB1    64               // stage-1 db rows per block
#define NCH1   (NDBP / NB1)     // 1564
#define QB2    256              // stage-2 q rows per block
#define NB     128              // stage-2 db rows per block
#define KT     64               // K elems per stage chunk (one i8 MFMA K-step)
#define NKIT   (ND / KT)        // 8
#define NCHUNK (NDBP / NB)      // 782

// Candidate filtering
#define Z0    3.125f            // stage-1 threshold = Z0 * ||row||
#define Z2    3.3f              // stage-2 threshold (10th-best ~ 4.29||q||)
#define QSC   32.0f             // i8 quantization scale
#define CAP   384               // max candidates per row
#define NROWT (NQ + R2)         // 1408 rows with thresholds

typedef int i32x4 __attribute__((ext_vector_type(4)));

// counted-vmcnt pipeline barrier: wait + barrier fused in one asm so nothing
// can be scheduled between; memory clobber pins all LDS/global ops.
#define PIPE_BAR(VM) asm volatile("s_waitcnt vmcnt(" #VM ")\n\ts_barrier" ::: "memory")
#define LGKM_BAR()   asm volatile("s_waitcnt lgkmcnt(0)\n\ts_barrier" ::: "memory")

__device__ __forceinline__ void gload_lds16(const void* gsrc, void* ldst) {
    __builtin_amdgcn_global_load_lds(
        (const __attribute__((address_space(1))) unsigned int*)gsrc,
        (__attribute__((address_space(3))) unsigned int*)ldst, 16, 0, 0);
}

__device__ __forceinline__ signed char f2i8(float x) {
    int v = (int)rintf(x * QSC);
    v = v > 127 ? 127 : v;
    v = v < -127 ? -127 : v;
    return (signed char)v;
}

// ---------------------------------------------------------------------------
// Stage-1 query prep: quantize to i8, integer threshold, zero cnt row.
// ---------------------------------------------------------------------------
__global__ __launch_bounds__(256) void prep_q_kernel(
    const float* __restrict__ src, signed char* __restrict__ dst,
    int* __restrict__ thrI, int* __restrict__ cnt)
{
    const int row = blockIdx.x;
    const int t = (int)threadIdx.x;
    __shared__ float red[4];
    const float a = src[(size_t)row * ND + t];
    const float b = src[(size_t)row * ND + t + 256];
    dst[(size_t)row * ND + t] = f2i8(a);
    dst[(size_t)row * ND + t + 256] = f2i8(b);
    float ss = a * a + b * b;
    for (int off = 32; off; off >>= 1) ss += __shfl_xor(ss, off);
    if ((t & 63) == 0) red[t >> 6] = ss;
    __syncthreads();
    if (t == 0) {
        const float tot = red[0] + red[1] + red[2] + red[3];
        thrI[row] = (int)(QSC * QSC * Z0 * sqrtf(tot));
        cnt[row] = 0;
    }
}

// ---------------------------------------------------------------------------
// Stage-1 FUSED cvt+GEMM (pathA) — r17 measured-best configuration.
//   phase 1: dense streaming f32->i8 of own 64-row chunk -> global dbi8,
//            3-deep register pipeline (fully unrolled).
//   barrier: __syncthreads drains vmcnt -> stores L2-visible.
//   phase 2: PIPE_BAR(3) pipelined GEMM reading chunk back via
//            global_load_lds (L2 hit). LDS 24 KB.
// ---------------------------------------------------------------------------
__global__ __launch_bounds__(256) void gemm1c_kernel(
    const signed char* __restrict__ Qb,   // [NQ][512] i8
    const float* __restrict__ Df,         // [NDB][512] f32
    signed char* __restrict__ DbOut,      // [NDBP][512] i8 out
    const int* __restrict__ thrI,
    int* __restrict__ candCnt, int* __restrict__ candId)
{
    __shared__ char lds[24576];           // [2 buf][Q 8KB | D 4KB]
    __shared__ int thrS[QB1];

    const int tid = (int)threadIdx.x;
    const int ln = tid & 63;
    const int wv = tid >> 6;
    const int wr = wv >> 1;               // 0..1 (q half of 128)
    const int wc = wv & 1;                // 0..1 (n half of 64)
    const int n0 = blockIdx.x * NB1;

    if (tid < QB1) thrS[tid] = thrI[tid];

    // ---- phase 1: own-chunk cvt, 8 iters x 16 i8/thread, 3-deep pipeline ----
    {
        const size_t base = (size_t)n0 * ND;
        const size_t lim = (size_t)NDB * ND;
        float4 f[3][4];
        bool ok[3];
#pragma unroll
        for (int pp = 0; pp < 3; ++pp) {   // prologue: load iters 0..2
            const size_t o = base + (size_t)pp * 4096 + (size_t)tid * 16;
            ok[pp] = (o + 16 <= lim);
            const float4* p = (const float4*)(Df + (ok[pp] ? o : 0));
#pragma unroll
            for (int j = 0; j < 4; ++j) f[pp][j] = p[j];
        }
#pragma unroll
        for (int it = 0; it < 8; ++it) {
            const int cur = it % 3;        // compile-time after full unroll
            union { signed char c[16]; i32x4 v; } u;
            if (ok[cur]) {
#pragma unroll
                for (int j = 0; j < 4; ++j) {
                    u.c[j * 4 + 0] = f2i8(f[cur][j].x);
                    u.c[j * 4 + 1] = f2i8(f[cur][j].y);
                    u.c[j * 4 + 2] = f2i8(f[cur][j].z);
                    u.c[j * 4 + 3] = f2i8(f[cur][j].w);
                }
            } else {
#pragma unroll
                for (int j = 0; j < 16; ++j) u.c[j] = 0;
            }
            *(i32x4*)(DbOut + base + (size_t)it * 4096 + (size_t)tid * 16) = u.v;
            if (it + 3 < 8) {              // reload slot for iter it+3
                const size_t o = base + (size_t)(it + 3) * 4096 + (size_t)tid * 16;
                ok[cur] = (o + 16 <= lim);
                const float4* p = (const float4*)(Df + (ok[cur] ? o : 0));
#pragma unroll
                for (int j = 0; j < 4; ++j) f[cur][j] = p[j];
            }
        }
    }
    __syncthreads();   // drains vmcnt(0): stores visible in own L2

    i32x4 acc[4][2] = {};

    auto stageQ = [&](int kc, int buf) {
#pragma unroll
        for (int c = 0; c < 2; ++c) {
            const int U = c * 256 + tid;               // 512 units (8 KB)
            const int r = U >> 2;                      // 0..127
            const int u = (U & 3) ^ ((r >> 1) & 3);
            gload_lds16(Qb + (size_t)r * ND + kc + u * 16,
                        lds + buf * 12288 + U * 16);
        }
    };
    auto stageD = [&](int kc, int buf) {
        const int U = tid;                             // 256 units (4 KB)
        const int r = U >> 2;                          // 0..63
        const int u = (U & 3) ^ ((r >> 1) & 3);
        gload_lds16(DbOut + (size_t)(n0 + r) * ND + kc + u * 16,
                    lds + buf * 12288 + 8192 + U * 16);
    };
    auto compute = [&](int buf) {
        const char* Qt = lds + buf * 12288;
        const char* Dt = Qt + 8192;
        i32x4 a[4], b[2];
#pragma unroll
        for (int qt = 0; qt < 4; ++qt) {
            const int r = wr * 64 + qt * 16 + (ln & 15);
            const int u = (ln >> 4) ^ ((r >> 1) & 3);
            a[qt] = *(const i32x4*)(Qt + r * 64 + u * 16);
        }
#pragma unroll
        for (int nt = 0; nt < 2; ++nt) {
            const int r = wc * 32 + nt * 16 + (ln & 15);
            const int u = (ln >> 4) ^ ((r >> 1) & 3);
            b[nt] = *(const i32x4*)(Dt + r * 64 + u * 16);
        }
        __builtin_amdgcn_s_setprio(1);
#pragma unroll
        for (int qt = 0; qt < 4; ++qt)
#pragma unroll
            for (int nt = 0; nt < 2; ++nt)
                acc[qt][nt] = __builtin_amdgcn_mfma_i32_16x16x64_i8(
                    a[qt], b[nt], acc[qt][nt], 0, 0, 0);
        __builtin_amdgcn_s_setprio(0);
    };

    stageQ(0, 0); stageD(0, 0);
    stageQ(KT, 1); stageD(KT, 1);
#pragma unroll
    for (int it = 0; it < NKIT; ++it) {
        if (it < NKIT - 1) PIPE_BAR(3); else PIPE_BAR(0);
        const int buf = it & 1;
        compute(buf);
        LGKM_BAR();
        if (it + 2 < NKIT) { stageQ((it + 2) * KT, buf); stageD((it + 2) * KT, buf); }
    }

    // Threshold filter. C/D layout: col=lane&15, row=(lane>>4)*4+reg.
    const int lg = ln >> 4;
    const int lc = ln & 15;
#pragma unroll
    for (int qt = 0; qt < 4; ++qt) {
#pragma unroll
        for (int c = 0; c < 4; ++c) {
            const int rloc = wr * 64 + qt * 16 + lg * 4 + c;
            const int T = thrS[rloc];
#pragma unroll
            for (int nt = 0; nt < 2; ++nt) {
                const int v = acc[qt][nt][c];
                if (v > T) {
                    const int n = n0 + wc * 32 + nt * 16 + lc;
                    if (n < NDB) {
                        const int slot = atomicAdd(&candCnt[rloc], 1);
                        if (slot < CAP) candId[(size_t)rloc * CAP + slot] = n;
                    }
                }
            }
        }
    }
}

// ---------------------------------------------------------------------------
// Stage-2 GEMM (pathA): XCD-aware chunk grouping (round-8 proven winner).
// Flat grid 3920 (= 8 XCDs x 490 slots). Block 512 = 8 waves (4x2),
// per-wave 64x64, acc[4][4]. LDS 48KB, PIPE_BAR(3) pipeline.
// ---------------------------------------------------------------------------
__global__ __launch_bounds__(512) void gemm2s_kernel(
    const signed char* __restrict__ Qb,   // [R2][512] i8
    const signed char* __restrict__ Db,   // [NDBP][512] i8
    const int* __restrict__ thrI,
    int* __restrict__ candCnt, int* __restrict__ candId)
{
    const int bid = (int)blockIdx.x;
    const int xcd = bid & 7;
    const int slot = bid >> 3;                       // 0..489
    const int nch_x = (xcd < 6) ? 98 : 97;
    if (slot >= nch_x * 5) return;
    const int cstart = (xcd < 6) ? 98 * xcd : 98 * 6 + 97 * (xcd - 6);
    const int chunk = cstart + slot / 5;
    const int qtile = slot % 5;

    __shared__ char lds[49152];           // [2 buf][Q 16KB | D 8KB]
    __shared__ int thrS[QB2];

    const int tid = (int)threadIdx.x;
    const int ln = tid & 63;
    const int wv = tid >> 6;              // 0..7
    const int wr = wv >> 1;               // 0..3 (q quarter)
    const int wc = wv & 1;                // 0..1 (n half)
    const int q0 = qtile * QB2;
    const int n0 = chunk * NB;

    if (tid < QB2) thrS[tid] = thrI[q0 + tid];

    i32x4 acc[4][4] = {};

    auto stageQ = [&](int kc, int buf) {
#pragma unroll
        for (int c = 0; c < 2; ++c) {
            const int U = c * 512 + tid;             // 1024 units (16 KB)
            const int r = U >> 2;                    // 0..255
            const int u = (U & 3) ^ ((r >> 1) & 3);
            gload_lds16(Qb + (size_t)(q0 + r) * ND + kc + u * 16,
                        lds + buf * 24576 + U * 16);
        }
    };
    auto stageD = [&](int kc, int buf) {
        const int U = tid;                           // 512 units (8 KB)
        const int r = U >> 2;                        // 0..127
        const int u = (U & 3) ^ ((r >> 1) & 3);
        gload_lds16(Db + (size_t)(n0 + r) * ND + kc + u * 16,
                    lds + buf * 24576 + 16384 + U * 16);
    };
    auto compute = [&](int buf) {
        const char* Qt = lds + buf * 24576;
        const char* Dt = Qt + 16384;
        i32x4 a[4], b[4];
#pragma unroll
        for (int qt = 0; qt < 4; ++qt) {
            const int r = wr * 64 + qt * 16 + (ln & 15);
            const int u = (ln >> 4) ^ ((r >> 1) & 3);
            a[qt] = *(const i32x4*)(Qt + r * 64 + u * 16);
        }
#pragma unroll
        for (int nt = 0; nt < 4; ++nt) {
            const int r = wc * 64 + nt * 16 + (ln & 15);
            const int u = (ln >> 4) ^ ((r >> 1) & 3);
            b[nt] = *(const i32x4*)(Dt + r * 64 + u * 16);
        }
        __builtin_amdgcn_s_setprio(1);
#pragma unroll
        for (int qt = 0; qt < 4; ++qt)
#pragma unroll
            for (int nt = 0; nt < 4; ++nt)
                acc[qt][nt] = __builtin_amdgcn_mfma_i32_16x16x64_i8(
                    a[qt], b[nt], acc[qt][nt], 0, 0, 0);
        __builtin_amdgcn_s_setprio(0);
    };

    __syncthreads();               // clean vmcnt slate
    stageQ(0, 0); stageD(0, 0);
    stageQ(KT, 1); stageD(KT, 1);
#pragma unroll
    for (int it = 0; it < NKIT; ++it) {
        if (it < NKIT - 1) PIPE_BAR(3); else PIPE_BAR(0);
        const int buf = it & 1;
        compute(buf);
        LGKM_BAR();
        if (it + 2 < NKIT) { stageQ((it + 2) * KT, buf); stageD((it + 2) * KT, buf); }
    }

    const int lg = ln >> 4;
    const int lc = ln & 15;
#pragma unroll
    for (int qt = 0; qt < 4; ++qt) {
#pragma unroll
        for (int c = 0; c < 4; ++c) {
            const int rloc = wr * 64 + qt * 16 + lg * 4 + c;
            const int row = q0 + rloc;
            const int T = thrS[rloc];
#pragma unroll
            for (int nt = 0; nt < 4; ++nt) {
                const int v = acc[qt][nt][c];
                if (v > T) {
                    const int n = n0 + wc * 64 + nt * 16 + lc;
                    if (n < NDB) {
                        const int slot2 = atomicAdd(&candCnt[row], 1);
                        if (slot2 < CAP) candId[(size_t)row * CAP + slot2] = n;
                    }
                }
            }
        }
    }
}

// ---------------------------------------------------------------------------
// Fallback (ws too small for dbi8): GEMM with in-register cvt (proven path).
// ---------------------------------------------------------------------------
__global__ __launch_bounds__(512) void gemm2_cvt_kernel(
    const signed char* __restrict__ Qb, const float* __restrict__ Df,
    const int* __restrict__ thrI, int* __restrict__ candCnt, int* __restrict__ candId,
    int qrows)
{
    __shared__ char lds[49152];
    __shared__ int thrS[QB2];
    const int tid = (int)threadIdx.x;
    const int ln = tid & 63;
    const int wv = tid >> 6;
    const int wr = wv >> 1;
    const int wc = wv & 1;
    const int q0 = blockIdx.x * QB2;
    const int n0 = blockIdx.y * NB;
    if (tid < QB2 && q0 + tid < qrows) thrS[tid] = thrI[q0 + tid];
    else if (tid < QB2) thrS[tid] = 0x7fffffff;

    i32x4 acc[4][4] = {};
    auto stageQ = [&](int kc, int buf) {
#pragma unroll
        for (int c = 0; c < 2; ++c) {
            const int U = c * 512 + tid;
            const int r = U >> 2;
            const int u = (U & 3) ^ ((r >> 1) & 3);
            const int gq = q0 + r;
            if (gq < qrows)
                gload_lds16(Qb + (size_t)gq * ND + kc + u * 16,
                            lds + buf * 24576 + U * 16);
            else
                *(i32x4*)(lds + buf * 24576 + U * 16) = i32x4{0, 0, 0, 0};
        }
    };
    auto stageDcvt = [&](int kc, int buf) {
        const int U = tid;
        const int r = U >> 2;
        const int u = (U & 3) ^ ((r >> 1) & 3);
        const int gn = n0 + r;
        union { signed char cc[16]; i32x4 v; } w;
        if (gn < NDB) {
#pragma unroll
            for (int j = 0; j < 4; ++j) {
                const float4 f = *(const float4*)(Df + (size_t)gn * ND + kc + u * 16 + j * 4);
                w.cc[j * 4 + 0] = f2i8(f.x);
                w.cc[j * 4 + 1] = f2i8(f.y);
                w.cc[j * 4 + 2] = f2i8(f.z);
                w.cc[j * 4 + 3] = f2i8(f.w);
            }
        } else {
#pragma unroll
            for (int j = 0; j < 16; ++j) w.cc[j] = 0;
        }
        *(i32x4*)(lds + buf * 24576 + 16384 + U * 16) = w.v;
    };
    stageQ(0, 0); stageDcvt(0, 0);
    for (int it = 0; it < NKIT; ++it) {
        const int buf = it & 1;
        __syncthreads();
        if (it + 1 < NKIT) { stageQ((it + 1) * KT, buf ^ 1); stageDcvt((it + 1) * KT, buf ^ 1); }
        const char* Qt = lds + buf * 24576;
        const char* Dt = Qt + 16384;
        i32x4 a[4], b[4];
#pragma unroll
        for (int qt = 0; qt < 4; ++qt) {
            const int r = wr * 64 + qt * 16 + (ln & 15);
            const int u = (ln >> 4) ^ ((r >> 1) & 3);
            a[qt] = *(const i32x4*)(Qt + r * 64 + u * 16);
        }
#pragma unroll
        for (int nt = 0; nt < 4; ++nt) {
            const int r = wc * 64 + nt * 16 + (ln & 15);
            const int u = (ln >> 4) ^ ((r >> 1) & 3);
            b[nt] = *(const i32x4*)(Dt + r * 64 + u * 16);
        }
#pragma unroll
        for (int qt = 0; qt < 4; ++qt)
#pragma unroll
            for (int nt = 0; nt < 4; ++nt)
                acc[qt][nt] = __builtin_amdgcn_mfma_i32_16x16x64_i8(
                    a[qt], b[nt], acc[qt][nt], 0, 0, 0);
        __syncthreads();
    }
    const int lg = ln >> 4;
    const int lc = ln & 15;
#pragma unroll
    for (int qt = 0; qt < 4; ++qt) {
#pragma unroll
        for (int c = 0; c < 4; ++c) {
            const int rloc = wr * 64 + qt * 16 + lg * 4 + c;
            const int row = q0 + rloc;
            if (row >= qrows) continue;
            const int T = thrS[rloc];
#pragma unroll
            for (int nt = 0; nt < 4; ++nt) {
                const int v = acc[qt][nt][c];
                if (v > T) {
                    const int n = n0 + wc * 64 + nt * 16 + lc;
                    if (n < NDB) {
                        const int slot = atomicAdd(&candCnt[row], 1);
                        if (slot < CAP) candId[(size_t)row * CAP + slot] = n;
                    }
                }
            }
        }
    }
}

// ---------------------------------------------------------------------------
// Candidate rescore helper: 2 candidates per wave per iteration (ILP).
// ---------------------------------------------------------------------------
__device__ __forceinline__ void rescore_cands(
    const float* __restrict__ db, const int* __restrict__ candId,
    size_t base, int nc, int wv, int ln,
    const float* qs, float* sc, int* sid)
{
    const float4 qa = *(const float4*)&qs[ln * 8];
    const float4 qb = *(const float4*)&qs[ln * 8 + 4];
    for (int i0 = wv * 2; i0 < nc; i0 += 8) {
        const int i1 = i0 + 1;
        const bool has1 = (i1 < nc);
        const int idA = candId[base + i0];
        const int idB = has1 ? candId[base + i1] : idA;
        const float4* dA = (const float4*)(db + (size_t)idA * ND);
        const float4* dB = (const float4*)(db + (size_t)idB * ND);
        const float4 a0 = dA[ln * 2];
        const float4 a1 = dA[ln * 2 + 1];
        const float4 b0 = dB[ln * 2];
        const float4 b1 = dB[ln * 2 + 1];
        float sA = qa.x * a0.x + qa.y * a0.y + qa.z * a0.z + qa.w * a0.w
                 + qb.x * a1.x + qb.y * a1.y + qb.z * a1.z + qb.w * a1.w;
        float sB = qa.x * b0.x + qa.y * b0.y + qa.z * b0.z + qa.w * b0.w
                 + qb.x * b1.x + qb.y * b1.y + qb.z * b1.z + qb.w * b1.w;
        for (int off = 32; off; off >>= 1) {
            sA += __shfl_xor(sA, off);
            sB += __shfl_xor(sB, off);
        }
        if (ln == 0) {
            sc[i0] = sA; sid[i0] = idA;
            if (has1) { sc[i1] = sB; sid[i1] = idB; }
        }
    }
}

// ---------------------------------------------------------------------------
// Stage-1 rescore (exact fp32 top-10) FUSED with gather/query_top_k/stage-2
// prep: writes s1I, q2i8, qtk, thrI2 (Z2), zeroes cnt2. One block/query.
// ---------------------------------------------------------------------------
__global__ __launch_bounds__(256) void rescore_fuse_kernel(
    const float* __restrict__ Qf,            // [NQ][512]
    const float* __restrict__ db,            // [NDB][512]
    const int* __restrict__ candCnt, const int* __restrict__ candId,
    int* __restrict__ s1I,
    signed char* __restrict__ q2i8,
    float* __restrict__ qtk,
    int* __restrict__ thrI2, int* __restrict__ cnt2)
{
    const int b = blockIdx.x;
    const int tid = (int)threadIdx.x;
    const int ln = tid & 63;
    const int wv = tid >> 6;

    __shared__ float qs[ND];
    __shared__ float sc[CAP];
    __shared__ int   sid[CAP];
    __shared__ float rbs[4];
    __shared__ int   rbi[4], rbsl[4];
    __shared__ int   topI[MM];
    __shared__ float red[11][4];

    qs[tid] = Qf[(size_t)b * ND + tid];
    qs[tid + 256] = Qf[(size_t)b * ND + tid + 256];
    const int nc = min(candCnt[b], CAP);
    for (int i = tid; i < CAP; i += 256) { sc[i] = -INFINITY; sid[i] = 0x7fffffff; }
    __syncthreads();

    rescore_cands(db, candId, (size_t)b * CAP, nc, wv, ln, qs, sc, sid);
    __syncthreads();

    for (int it = 0; it < KK; ++it) {
        float bs = -INFINITY;
        int bid = 0x7fffffff, bsl = -1;
        for (int i = tid; i < nc; i += 256) {
            const float s = sc[i];
            if (s > bs || (s == bs && sid[i] < bid)) { bs = s; bid = sid[i]; bsl = i; }
        }
        for (int off = 32; off; off >>= 1) {
            const float os = __shfl_xor(bs, off);
            const int oi = __shfl_xor(bid, off);
            const int osl = __shfl_xor(bsl, off);
            if (os > bs || (os == bs && oi < bid)) { bs = os; bid = oi; bsl = osl; }
        }
        if (ln == 0) { rbs[wv] = bs; rbi[wv] = bid; rbsl[wv] = bsl; }
        __syncthreads();
        if (tid == 0) {
            float fb = -INFINITY; int fi = 0x7fffffff, fs = -1;
#pragma unroll
            for (int w = 0; w < 4; ++w) {
                if (rbs[w] > fb || (rbs[w] == fb && rbi[w] < fi)) {
                    fb = rbs[w]; fi = rbi[w]; fs = rbsl[w];
                }
            }
            const int idw = (fi == 0x7fffffff) ? 0 : fi;
            s1I[b * MM + it] = idw;
            topI[it] = idw;
            if (fs >= 0) sc[fs] = -INFINITY;
        }
        __syncthreads();
    }

    // ---- phase 2: gather top_m, qtk, q2 prep ----
    const float q0v = qs[tid];
    const float q1v = qs[tid + 256];
    float mx0 = q0v, mx1 = q1v;
    float ssq[MM];
#pragma unroll
    for (int m = 0; m < MM; ++m) {
        const int id = topI[m];
        const float v0 = db[(size_t)id * ND + tid];
        const float v1 = db[(size_t)id * ND + tid + 256];
        const size_t rowo = (size_t)(b * MM + m) * ND;
        q2i8[rowo + tid] = f2i8(v0);
        q2i8[rowo + tid + 256] = f2i8(v1);
        ssq[m] = v0 * v0 + v1 * v1;
        if (m < KK - 1) { mx0 = fmaxf(mx0, v0); mx1 = fmaxf(mx1, v1); }
    }
    float sqq = mx0 * mx0 + mx1 * mx1;
#pragma unroll
    for (int m = 0; m < MM; ++m) {
        float s = ssq[m];
        for (int off = 32; off; off >>= 1) s += __shfl_xor(s, off);
        if (ln == 0) red[m][wv] = s;
    }
    for (int off = 32; off; off >>= 1) sqq += __shfl_xor(sqq, off);
    if (ln == 0) red[10][wv] = sqq;
    __syncthreads();
    if (tid < MM) {
        const float tot = red[tid][0] + red[tid][1] + red[tid][2] + red[tid][3];
        thrI2[b * MM + tid] = (int)(QSC * QSC * Z2 * sqrtf(tot));
        cnt2[b * MM + tid] = 0;
    }
    const float tq = red[10][0] + red[10][1] + red[10][2] + red[10][3];
    const float inv = 1.0f / fmaxf(sqrtf(tq), 1e-12f);
    qtk[(size_t)b * ND + tid] = mx0 * inv;
    qtk[(size_t)b * ND + tid + 256] = mx1 * inv;
}

// ---------------------------------------------------------------------------
// Stage-2 exact fp32 rescore + top-10 FUSED with refinement + final score.
// One block per (b, m) row; stage-2 query row read via s1I indirection.
// ---------------------------------------------------------------------------
__global__ __launch_bounds__(256) void rescore_refine_kernel(
    const int* __restrict__ s1I,             // [NQ*MM] stage-2 query db-ids
    const float* __restrict__ q,             // [NQ][512] original queries
    const float* __restrict__ qtk,           // [NQ][512] normalized query_top_k
    const float* __restrict__ db,
    const int* __restrict__ candCnt, const int* __restrict__ candId,
    float* __restrict__ finalS)
{
    const int row = blockIdx.x;              // b*MM + m
    const int b = row / MM;
    const int tid = (int)threadIdx.x;
    const int ln = tid & 63;
    const int wv = tid >> 6;

    __shared__ float qs[ND];
    __shared__ float sc[CAP];
    __shared__ int   sid[CAP];
    __shared__ float rbs[4];
    __shared__ int   rbi[4], rbsl[4];
    __shared__ float topS[KK];
    __shared__ int   topI[KK];
    __shared__ float red[3][4];

    const int qid = s1I[row];                // stage-2 query = db[qid]
    qs[tid] = db[(size_t)qid * ND + tid];
    qs[tid + 256] = db[(size_t)qid * ND + tid + 256];
    const int nc = min(candCnt[row], CAP);
    for (int i = tid; i < CAP; i += 256) { sc[i] = -INFINITY; sid[i] = 0x7fffffff; }
    __syncthreads();

    rescore_cands(db, candId, (size_t)row * CAP, nc, wv, ln, qs, sc, sid);
    __syncthreads();

    for (int it = 0; it < KK; ++it) {
        float bs = -INFINITY;
        int bid = 0x7fffffff, bsl = -1;
        for (int i = tid; i < nc; i += 256) {
            const float s = sc[i];
            if (s > bs || (s == bs && sid[i] < bid)) { bs = s; bid = sid[i]; bsl = i; }
        }
        for (int off = 32; off; off >>= 1) {
            const float os = __shfl_xor(bs, off);
            const int oi = __shfl_xor(bid, off);
            const int osl = __shfl_xor(bsl, off);
            if (os > bs || (os == bs && oi < bid)) { bs = os; bid = oi; bsl = osl; }
        }
        if (ln == 0) { rbs[wv] = bs; rbi[wv] = bid; rbsl[wv] = bsl; }
        __syncthreads();
        if (tid == 0) {
            float fb = -INFINITY; int fi = 0x7fffffff, fs = -1;
#pragma unroll
            for (int w = 0; w < 4; ++w) {
                if (rbs[w] > fb || (rbs[w] == fb && rbi[w] < fi)) {
                    fb = rbs[w]; fi = rbi[w]; fs = rbsl[w];
                }
            }
            if (!(fb > -INFINITY)) { fb = 0.f; fi = 0; }
            topS[it] = fb;
            topI[it] = (fi == 0x7fffffff) ? 0 : fi;
            if (fs >= 0) sc[fs] = -INFINITY;
        }
        __syncthreads();
    }

    // ---- refinement phase, top-10 rows L2-hot ----
    float ssum = 0.f;
#pragma unroll
    for (int m = 0; m < KK; ++m) ssum += topS[m];
    const float nf = 3.f + 2.f * ssum;

    const float q0v = q[(size_t)b * ND + tid];
    const float q1v = q[(size_t)b * ND + tid + 256];
    float w0 = 2.f * q0v;
    float w1 = 2.f * q1v;
#pragma unroll
    for (int m = 0; m < KK; ++m) {
        const int id = topI[m];
        const float w = 2.f * topS[m];
        w0 = fmaf(w, db[(size_t)id * ND + tid], w0);
        w1 = fmaf(w, db[(size_t)id * ND + tid + 256], w1);
    }
    w0 /= nf;
    w1 /= nf;

    float s_n = w0 * w0 + w1 * w1;
    float s_1 = w0 * q0v + w1 * q1v;
    float s_2 = w0 * qtk[(size_t)b * ND + tid] + w1 * qtk[(size_t)b * ND + tid + 256];
    for (int off = 32; off; off >>= 1) {
        s_n += __shfl_xor(s_n, off);
        s_1 += __shfl_xor(s_1, off);
        s_2 += __shfl_xor(s_2, off);
    }
    if (ln == 0) { red[0][wv] = s_n; red[1][wv] = s_1; red[2][wv] = s_2; }
    __syncthreads();
    if (tid == 0) {
        const float tn = red[0][0] + red[0][1] + red[0][2] + red[0][3];
        const float t1 = red[1][0] + red[1][1] + red[1][2] + red[1][3];
        const float t2 = red[2][0] + red[2][1] + red[2][2] + red[2][3];
        const float inv = 1.0f / fmaxf(sqrtf(tn), 1e-12f);
        finalS[row] = 0.5f * (t1 * inv + t2 * inv);
    }
}

// ---------------------------------------------------------------------------
// Final top-3 of 10 per query; ids (as float) then scores.
// ---------------------------------------------------------------------------
__global__ __launch_bounds__(64) void final_topk_kernel(
    const float* __restrict__ finalS, const int* __restrict__ s1I,
    float* __restrict__ out)
{
    const int b = blockIdx.x * 64 + (int)threadIdx.x;
    if (b >= NQ) return;
    float s[MM];
#pragma unroll
    for (int m = 0; m < MM; ++m) s[m] = finalS[b * MM + m];
#pragma unroll
    for (int x = 0; x < TOPX; ++x) {
        float bs = -INFINITY;
        int bm = 0;
#pragma unroll
        for (int m = 0; m < MM; ++m) {
            if (s[m] > bs) { bs = s[m]; bm = m; }
        }
        out[b * TOPX + x] = (float)s1I[b * MM + bm];
        out[NQ * TOPX + b * TOPX + x] = bs;
        s[bm] = -INFINITY;
    }
}

// ---------------------------------------------------------------------------
extern "C" void kernel_launch(void* const* d_in, const int* in_sizes, int n_in,
                              void* d_out, int out_size, void* d_ws, size_t ws_size,
                              hipStream_t stream)
{
    const float* q = (const float*)d_in[0];
    const float* db = (const float*)d_in[1];
    float* out = (float*)d_out;

    char* ws = (char*)d_ws;
    size_t off = 0;
    auto alloc = [&](size_t bytes) -> void* {
        void* p = ws + off;
        off += (bytes + 255) & ~(size_t)255;
        return p;
    };
    signed char* qi8  = (signed char*)alloc((size_t)NQ * ND);
    signed char* q2i8 = (signed char*)alloc((size_t)R2 * ND);
    float* qtk  = (float*)alloc(sizeof(float) * NQ * ND);
    int*   thrI = (int*)alloc(sizeof(int) * NROWT);
    int*   cnt  = (int*)alloc(sizeof(int) * NROWT);
    int*   cid  = (int*)alloc(sizeof(int) * (size_t)NROWT * CAP);
    int*   s1I  = (int*)alloc(sizeof(int) * NQ * MM);
    float* fS   = (float*)alloc(sizeof(float) * NQ * MM);
    signed char* dbi8 = (signed char*)alloc((size_t)NDBP * ND);   // 51.25 MB
    const bool pathA = (ws_size >= off);

    // Stage-1 prep (quantize queries, thresholds, zero cnt rows 0..NQ)
    prep_q_kernel<<<NQ, 256, 0, stream>>>(q, qi8, thrI, cnt);

    if (pathA) {
        // Fused: per-chunk dense cvt (3-deep pipelined) -> global dbi8 ->
        // pipelined i8 GEMM readback (L2-hot). One dispatch for all stage 1.
        gemm1c_kernel<<<NCH1, 256, 0, stream>>>(qi8, db, dbi8, thrI, cnt, cid);
    } else {
        gemm2_cvt_kernel<<<dim3(1, NCHUNK), 512, 0, stream>>>(
            qi8, db, thrI, cnt, cid, NQ);
    }

    // Stage-1 exact rescore fused with gather/qtk/stage-2 prep
    rescore_fuse_kernel<<<NQ, 256, 0, stream>>>(
        q, db, cnt, cid, s1I, q2i8, qtk, thrI + NQ, cnt + NQ);

    // Stage 2: candidates (pipelined i8 GEMM, XCD-grouped)
    if (pathA)
        gemm2s_kernel<<<3920, 512, 0, stream>>>(
            q2i8, dbi8, thrI + NQ, cnt + NQ, cid + (size_t)NQ * CAP);
    else
        gemm2_cvt_kernel<<<dim3(R2 / QB2, NCHUNK), 512, 0, stream>>>(
            q2i8, db, thrI + NQ, cnt + NQ, cid + (size_t)NQ * CAP, R2);

    // Stage-2 exact rescore + refinement + final scores (fused)
    rescore_refine_kernel<<<R2, 256, 0, stream>>>(
        s1I, q, qtk, db, cnt + NQ, cid + (size_t)NQ * CAP, fS);

    // Final top-3 -> output
    final_topk_kernel<<<(NQ + 63) / 64, 64, 0, stream>>>(fS, s1I, out);
    (void)in_sizes; (void)n_in; (void)out_size;
}